// Round 1
// baseline (545.540 us; speedup 1.0000x reference)
//
#include <hip/hip_runtime.h>
#include <stdint.h>

#define B_ 16
#define N_ 25200
#define NC_ 80
#define ROW_ 85
#define TOPK_ 1024
#define MAXDET_ 300
#define CONF_T 0.25f
#define IOU_T 0.45f
#define MAX_WH_ 4096.0f

// ---------------------------------------------------------------------------
// Kernel A: per (b,n) compute conf = max_c(obj * cls_c), validity-masked, and
// emit a unique 64-bit sort key: conf_bits<<32 | (0xFFFFFFFF - n).
// Descending key order == lax.top_k order (value desc, index asc).
// ---------------------------------------------------------------------------
__global__ void score_kernel(const float* __restrict__ det,
                             unsigned long long* __restrict__ keys) {
#pragma clang fp contract(off)
    int n = blockIdx.x * blockDim.x + threadIdx.x;
    int b = blockIdx.y;
    if (n >= N_) return;
    const float* row = det + ((size_t)b * N_ + n) * ROW_;
    float obj = row[4];
    float m = -1.0f;
#pragma unroll 4
    for (int c = 0; c < NC_; ++c) {
        float p = obj * row[5 + c];
        m = (p > m) ? p : m;
    }
    float conf = (obj > CONF_T && m > CONF_T) ? m : 0.0f;
    keys[(size_t)b * N_ + n] =
        ((unsigned long long)__float_as_uint(conf) << 32) |
        (unsigned int)(0xFFFFFFFFu - (unsigned int)n);
}

// ---------------------------------------------------------------------------
// Kernel B: one block (1024 threads) per batch image.
//  1. radix-select exact 1024th-largest key (8 passes of 8 bits)
//  2. compact the 1024 selected keys, rank-sort them in LDS (exact, stable)
//  3. gather rows, recompute cls/box exactly as reference
//  4. greedy NMS (serial over i, parallel over j) with reference FP order
//  5. write kept rows (first 300) to out; rest stays zeroed
// ---------------------------------------------------------------------------
__global__ void __launch_bounds__(1024) nms_kernel(const float* __restrict__ det,
                                                   const unsigned long long* __restrict__ keys,
                                                   float* __restrict__ out) {
#pragma clang fp contract(off)
    const int b = blockIdx.x;
    const int t = threadIdx.x;

    __shared__ unsigned int hist[256];
    __shared__ unsigned long long s_prefix;
    __shared__ int s_k;
    __shared__ int s_cnt;
    __shared__ unsigned long long selk[TOPK_];
    __shared__ float bx1[TOPK_], by1[TOPK_], bx2[TOPK_], by2[TOPK_];
    __shared__ float areas[TOPK_];
    __shared__ int keep[TOPK_];
    __shared__ int wave_cnt[16], wave_off[16];

    const unsigned long long* bkeys = keys + (size_t)b * N_;

    // zero this batch's output (harness poisons d_out once; we own zeros)
    for (int i = t; i < MAXDET_ * 6; i += 1024) out[(size_t)b * MAXDET_ * 6 + i] = 0.0f;

    // ---- 1. radix select: find T = 1024th largest key (keys are unique) ----
    unsigned long long prefix = 0;
    int k = TOPK_;
    for (int shift = 56; shift >= 0; shift -= 8) {
        if (t < 256) hist[t] = 0;
        __syncthreads();
        for (int n = t; n < N_; n += 1024) {
            unsigned long long key = bkeys[n];
            bool match = (shift == 56) || ((key >> (shift + 8)) == prefix);
            if (match) atomicAdd(&hist[(unsigned)(key >> shift) & 255u], 1u);
        }
        __syncthreads();
        if (t == 0) {
            int run = 0;
            int d = 255;
            for (; d > 0; --d) {
                int c = (int)hist[d];
                if (run + c >= k) break;
                run += c;
            }
            s_k = k - run;
            s_prefix = (prefix << 8) | (unsigned long long)d;
        }
        __syncthreads();
        prefix = s_prefix;
        k = s_k;
        __syncthreads();  // keep hist stable until t==0's scan is consumed
    }
    const unsigned long long T = prefix;

    // ---- 2a. compaction: exactly TOPK_ keys satisfy key >= T ----
    if (t == 0) s_cnt = 0;
    __syncthreads();
    for (int n = t; n < N_; n += 1024) {
        unsigned long long key = bkeys[n];
        if (key >= T) {
            int pos = atomicAdd(&s_cnt, 1);
            if (pos < TOPK_) selk[pos] = key;
        }
    }
    __syncthreads();

    // ---- 2b. rank sort (keys unique -> ranks are a permutation) ----
    unsigned long long myk = selk[t];
    int rank = 0;
    for (int i = 0; i < TOPK_; ++i) rank += (selk[i] > myk) ? 1 : 0;
    __syncthreads();
    selk[rank] = myk;   // selk becomes descending-sorted
    __syncthreads();

    // ---- 3. gather + exact recompute of cls/box ----
    unsigned long long kk = selk[t];
    int n_idx = (int)(0xFFFFFFFFu - (unsigned int)kk);
    float conf = __uint_as_float((unsigned int)(kk >> 32));
    const float* row = det + ((size_t)b * N_ + n_idx) * ROW_;
    float xc = row[0], yc = row[1], w = row[2], h = row[3];
    float obj = row[4];
    float m = -1.0f;
    int cls = 0;
    for (int c = 0; c < NC_; ++c) {
        float p = obj * row[5 + c];
        if (p > m) { m = p; cls = c; }   // strict > == first-max (jnp.argmax)
    }
    float hw = w * 0.5f, hh = h * 0.5f;
    float x1 = xc - hw, y1 = yc - hh, x2 = xc + hw, y2 = yc + hh;
    float off = (float)cls * MAX_WH_;
    float X1 = x1 + off, Y1 = y1 + off, X2 = x2 + off, Y2 = y2 + off;
    bx1[t] = X1; by1[t] = Y1; bx2[t] = X2; by2[t] = Y2;
    float area = fmaxf(X2 - X1, 0.0f) * fmaxf(Y2 - Y1, 0.0f);
    areas[t] = area;
    int alive = (conf > 0.0f) ? 1 : 0;   // keep init = scores_k > 0
    keep[t] = alive;
    __syncthreads();

    // ---- 4. greedy NMS: serial over i, parallel over j=t ----
    for (int i = 0; i < TOPK_ - 1; ++i) {
        if (keep[i]) {                       // uniform across block
            if (t > i && alive) {
                float lx = fmaxf(bx1[i], X1);
                float ly = fmaxf(by1[i], Y1);
                float rx = fminf(bx2[i], X2);
                float ry = fminf(by2[i], Y2);
                float iw = fmaxf(rx - lx, 0.0f);
                float ih = fmaxf(ry - ly, 0.0f);
                float inter = iw * ih;
                float uni = areas[i] + area - inter + 1e-7f;  // ((ai+aj)-inter)+eps
                if (inter / uni > IOU_T) { alive = 0; keep[t] = 0; }
            }
        }
        __syncthreads();
    }

    // ---- 5. rank kept entries, write first 300 ----
    unsigned long long ball = __ballot(alive != 0);
    int wid = t >> 6, lane = t & 63;
    if (lane == 0) wave_cnt[wid] = __popcll(ball);
    __syncthreads();
    if (t == 0) {
        int acc = 0;
        for (int wv = 0; wv < 16; ++wv) { wave_off[wv] = acc; acc += wave_cnt[wv]; }
    }
    __syncthreads();
    if (alive) {
        unsigned long long below = (lane == 0) ? 0ull : (ball & ((1ull << lane) - 1ull));
        int r = wave_off[wid] + __popcll(below);
        if (r < MAXDET_) {
            float* o = out + ((size_t)b * MAXDET_ + r) * 6;
            o[0] = x1; o[1] = y1; o[2] = x2; o[3] = y2;
            o[4] = conf; o[5] = (float)cls;
        }
    }
}

extern "C" void kernel_launch(void* const* d_in, const int* in_sizes, int n_in,
                              void* d_out, int out_size, void* d_ws, size_t ws_size,
                              hipStream_t stream) {
    const float* det = (const float*)d_in[0];
    float* out = (float*)d_out;
    unsigned long long* keys = (unsigned long long*)d_ws;  // B_*N_*8 = 3.2MB

    dim3 gridA((N_ + 255) / 256, B_);
    score_kernel<<<gridA, 256, 0, stream>>>(det, keys);
    nms_kernel<<<B_, 1024, 0, stream>>>(det, keys, out);
}

// Round 2
// 307.286 us; speedup vs baseline: 1.7753x; 1.7753x over previous
//
#include <hip/hip_runtime.h>
#include <stdint.h>

#define B_ 16
#define N_ 25200
#define NC_ 80
#define ROW_ 85
#define TOPK_ 1024
#define MAXDET_ 300
#define CONF_T 0.25f
#define IOU_T 0.45f
#define MAX_WH_ 4096.0f

typedef unsigned long long u64;
typedef unsigned int u32;

// ws layout (bytes)
#define OFF_KEYS  0ull                      // 16*25200*8 = 3,225,600
#define OFF_SELK  3225600ull                // 16*1024*8  =   131,072
#define OFF_OBOX  3356672ull                // 16*1024*16 =   262,144 (float4)
#define OFF_OAR   3618816ull                // 16*1024*4  =    65,536
#define OFF_PAY   3684352ull                // 16*1024*24 =   393,216
#define OFF_VALID 4077568ull                // 16*1024*4  =    65,536
#define OFF_MASK  4143104ull                // 16*1024*16*8 = 2,097,152  -> end 6,240,256

// ---------------------------------------------------------------------------
// K1: LDS-staged, coalesced score computation.
// key = conf_bits<<32 | (0xFFFFFFFF - n)  (unique; desc order == lax.top_k)
// ---------------------------------------------------------------------------
#define K1_ROWS 128
__global__ void __launch_bounds__(256) score_kernel(const float* __restrict__ det,
                                                    u64* __restrict__ keys) {
#pragma clang fp contract(off)
    __shared__ float s[K1_ROWS * ROW_];
    const int b = blockIdx.y;
    const int r0 = blockIdx.x * K1_ROWS;
    const int rows = min(K1_ROWS, N_ - r0);
    const int t = threadIdx.x;
    const float* src = det + ((size_t)b * N_ + r0) * ROW_;
    const int cnt = rows * ROW_;
    for (int i = t; i < cnt; i += 256) s[i] = src[i];
    __syncthreads();
    if (t < rows) {
        const float* row = s + t * ROW_;
        float obj = row[4];
        float m = -1.0f;
#pragma unroll 8
        for (int c = 0; c < NC_; ++c) {
            float p = obj * row[5 + c];
            m = (p > m) ? p : m;
        }
        float conf = (obj > CONF_T && m > CONF_T) ? m : 0.0f;
        int n = r0 + t;
        keys[(size_t)b * N_ + n] =
            ((u64)__float_as_uint(conf) << 32) | (u32)(0xFFFFFFFFu - (u32)n);
    }
}

// ---------------------------------------------------------------------------
// K2: exact radix-select of top-1024 keys per batch (one 1024-thr block each).
// Per-wave histograms (stride 257) kill same-address atomic serialization;
// candidate set is compacted into LDS once it fits (<=4096) so later passes
// and re-scans stay on-chip. Output: 1024 selected keys (unsorted).
// ---------------------------------------------------------------------------
#define CBUF_CAP 4096
__global__ void __launch_bounds__(1024) select_kernel(const u64* __restrict__ keys,
                                                      u64* __restrict__ selk) {
    const int b = blockIdx.x;
    const int t = threadIdx.x;
    const int wave = t >> 6;
    __shared__ u32 whist[16 * 257];
    __shared__ u32 hist[256];
    __shared__ u64 s_prefix;
    __shared__ int s_k, s_c, s_cnt;
    __shared__ u64 cbuf[CBUF_CAP];

    const u64* bkeys = keys + (size_t)b * N_;

    u64 prefix = 0;
    int k = TOPK_;
    bool compacted = false;
    int ccount = 0;

    for (int shift = 56; shift >= 0; shift -= 8) {
        for (int i = t; i < 16 * 257; i += 1024) whist[i] = 0;
        __syncthreads();
        if (!compacted) {
            for (int n = t; n < N_; n += 1024) {
                u64 key = bkeys[n];
                if (shift == 56 || (key >> (shift + 8)) == prefix)
                    atomicAdd(&whist[wave * 257 + (int)((key >> shift) & 255u)], 1u);
            }
        } else {
            for (int n = t; n < ccount; n += 1024) {
                u64 key = cbuf[n];
                if ((key >> (shift + 8)) == prefix)
                    atomicAdd(&whist[wave * 257 + (int)((key >> shift) & 255u)], 1u);
            }
        }
        __syncthreads();
        if (t < 256) {
            u32 ssum = 0;
#pragma unroll
            for (int w = 0; w < 16; ++w) ssum += whist[w * 257 + t];
            hist[t] = ssum;
        }
        __syncthreads();
        if (t == 0) {
            int run = 0;
            int d = 255;
            for (; d > 0; --d) {
                int c = (int)hist[d];
                if (run + c >= k) break;
                run += c;
            }
            s_k = k - run;
            s_c = (int)hist[d];
            s_prefix = (prefix << 8) | (u64)d;
        }
        __syncthreads();
        prefix = s_prefix;
        k = s_k;
        int c = s_c;
        __syncthreads();

        if (!compacted && shift > 0 && c <= CBUF_CAP) {
            if (t == 0) s_cnt = 0;
            __syncthreads();
            for (int n = t; n < N_; n += 1024) {
                u64 key = bkeys[n];
                if ((key >> shift) == prefix) {
                    int pos = atomicAdd(&s_cnt, 1);
                    cbuf[pos] = key;
                }
            }
            __syncthreads();
            ccount = s_cnt;
            compacted = true;
            __syncthreads();
        }
    }
    const u64 T = prefix;  // exact 1024th-largest key

    // gather all keys >= T (exactly 1024, keys unique)
    if (t == 0) s_cnt = 0;
    __syncthreads();
    for (int n = t; n < N_; n += 1024) {
        u64 key = bkeys[n];
        if (key >= T) {
            int pos = atomicAdd(&s_cnt, 1);
            if (pos < TOPK_) selk[(size_t)b * TOPK_ + pos] = key;
        }
    }
}

// ---------------------------------------------------------------------------
// K3: rank the 1024 keys (brute-force, 1 wave/CU so broadcast LDS reads don't
// contend), gather rows, recompute cls/boxes with reference FP order, write
// into sorted slots.
// ---------------------------------------------------------------------------
__global__ void __launch_bounds__(64) rank_kernel(const float* __restrict__ det,
                                                  const u64* __restrict__ selk,
                                                  float4* __restrict__ obox4,
                                                  float* __restrict__ oar,
                                                  float* __restrict__ pay,
                                                  int* __restrict__ valid) {
#pragma clang fp contract(off)
    __shared__ u64 sk[TOPK_];
    const int b = blockIdx.x >> 4;
    const int chunk = blockIdx.x & 15;
    const int t = threadIdx.x;
    for (int i = t; i < TOPK_; i += 64) sk[i] = selk[(size_t)b * TOPK_ + i];
    __syncthreads();
    u64 myk = sk[chunk * 64 + t];
    int rank = 0;
#pragma unroll 8
    for (int i = 0; i < TOPK_; ++i) rank += (sk[i] > myk) ? 1 : 0;

    int n_idx = (int)(0xFFFFFFFFu - (u32)myk);
    float conf = __uint_as_float((u32)(myk >> 32));
    const float* row = det + ((size_t)b * N_ + n_idx) * ROW_;
    float xc = row[0], yc = row[1], w = row[2], h = row[3];
    float obj = row[4];
    float m = -1.0f;
    int cls = 0;
    for (int c = 0; c < NC_; ++c) {
        float p = obj * row[5 + c];
        if (p > m) { m = p; cls = c; }   // strict > == jnp.argmax first-max
    }
    float hw = w * 0.5f, hh = h * 0.5f;
    float x1 = xc - hw, y1 = yc - hh, x2 = xc + hw, y2 = yc + hh;
    float off = (float)cls * MAX_WH_;
    float X1 = x1 + off, Y1 = y1 + off, X2 = x2 + off, Y2 = y2 + off;
    float area = fmaxf(X2 - X1, 0.0f) * fmaxf(Y2 - Y1, 0.0f);

    size_t o = (size_t)b * TOPK_ + rank;
    obox4[o] = make_float4(X1, Y1, X2, Y2);
    oar[o] = area;
    float* p6 = pay + o * 6;
    p6[0] = x1; p6[1] = y1; p6[2] = x2; p6[3] = y2;
    p6[4] = conf; p6[5] = (float)cls;
    valid[o] = (conf > 0.0f) ? 1 : 0;
}

// ---------------------------------------------------------------------------
// K4: mask[i][w] bit j-in-word = (j>i) && (iou(i,j) > IOU_T), reference FP
// order: uni = ((ai+aj)-inter)+1e-7, iou = inter/uni (real division).
// block: 16 rows x 16 words; j-index staggered by 5*w to stay conflict-free.
// ---------------------------------------------------------------------------
__global__ void __launch_bounds__(256) mask_kernel(const float4* __restrict__ obox4,
                                                   const float* __restrict__ oar,
                                                   u64* __restrict__ mask) {
#pragma clang fp contract(off)
    __shared__ float4 sbox[TOPK_];
    __shared__ float sar[TOPK_];
    const int b = blockIdx.y;
    const int t = threadIdx.x;
    for (int i = t; i < TOPK_; i += 256) {
        sbox[i] = obox4[(size_t)b * TOPK_ + i];
        sar[i] = oar[(size_t)b * TOPK_ + i];
    }
    __syncthreads();
    const int i = blockIdx.x * 16 + (t >> 4);
    const int w = t & 15;
    float4 bi = sbox[i];
    float ai = sar[i];
    u64 m = 0;
#pragma unroll 4
    for (int jj = 0; jj < 64; ++jj) {
        int jr = (jj + 5 * w) & 63;
        int j = (w << 6) | jr;
        float4 bj = sbox[j];
        float aj = sar[j];
        float lx = fmaxf(bi.x, bj.x);
        float ly = fmaxf(bi.y, bj.y);
        float rx = fminf(bi.z, bj.z);
        float ry = fminf(bi.w, bj.w);
        float iw = fmaxf(rx - lx, 0.0f);
        float ih = fmaxf(ry - ly, 0.0f);
        float inter = iw * ih;
        float uni = ai + aj - inter + 1e-7f;  // ((ai+aj)-inter)+1e-7
        bool sup = (inter / uni > IOU_T) && (j > i);
        m |= sup ? (1ull << jr) : 0ull;
    }
    mask[((size_t)b * TOPK_ + i) * 16 + w] = m;
}

// ---------------------------------------------------------------------------
// K5: single-wave greedy bit-scan per batch + output write.
// removed word (lane&15) held in registers; mask rows prefetched 8 groups
// (32 rows) ahead into a register ring. No barriers in the scan.
// ---------------------------------------------------------------------------
__global__ void __launch_bounds__(64) scan_kernel(const u64* __restrict__ mask,
                                                  const int* __restrict__ valid,
                                                  const float* __restrict__ pay,
                                                  float* __restrict__ out) {
    const int b = blockIdx.x;
    const int lane = threadIdx.x;
    const u64* bmask = mask + (size_t)b * TOPK_ * 16;

    // pack valid[] into 16 u64 words (lane w holds word w, w = lane&15 copies)
    u64 validbits = 0;
    for (int it = 0; it < 16; ++it) {
        int v = valid[(size_t)b * TOPK_ + it * 64 + lane];
        u64 bal = __ballot(v != 0);
        if ((lane & 15) == it && lane < 16) validbits = bal;
    }
    // broadcast so every lane's (lane&15) word is consistent
    validbits = __shfl(validbits, lane & 15);

    u64 removed = 0;

    // prefetch ring: group g = rows 4g..4g+3; lane supplies word (lane&15)
    // of row 4g + (lane>>4).
    u64 ring[8];
#pragma unroll
    for (int g = 0; g < 8; ++g) {
        int row = 4 * g + (lane >> 4);
        ring[g] = bmask[(size_t)row * 16 + (lane & 15)];
    }

    for (int i = 0; i < TOPK_; ++i) {
        const int g = i >> 2;
        const int sub = i & 3;
        u64 mrow = __shfl(ring[g & 7], (sub << 4) | (lane & 15));
        int wi = i >> 6;
        u64 remw = __shfl(removed, wi);
        u64 vw = __shfl(validbits, wi);
        bool alive_i = (((vw >> (i & 63)) & 1ull) != 0) &&
                       (((remw >> (i & 63)) & 1ull) == 0);
        if (alive_i) removed |= mrow;
        if (sub == 3) {
            int ng = g + 8;
            if (ng < TOPK_ / 4) {
                int row = 4 * ng + (lane >> 4);
                ring[g & 7] = bmask[(size_t)row * 16 + (lane & 15)];
            }
        }
    }

    u64 alive = validbits & ~removed;

    // write kept rows (rank order = i order), zero the tail
    int prefix = 0;
    for (int it = 0; it < 16; ++it) {
        u64 aw = __shfl(alive, it);
        int idx = it * 64 + lane;
        bool bit = ((aw >> lane) & 1ull) != 0;
        int rank = prefix + __popcll(aw & ((lane == 0) ? 0ull : ((1ull << lane) - 1ull)));
        if (bit && rank < MAXDET_) {
            const float* p6 = pay + ((size_t)b * TOPK_ + idx) * 6;
            float* o = out + ((size_t)b * MAXDET_ + rank) * 6;
            o[0] = p6[0]; o[1] = p6[1]; o[2] = p6[2];
            o[3] = p6[3]; o[4] = p6[4]; o[5] = p6[5];
        }
        prefix += __popcll(aw);
    }
    int kept = prefix < MAXDET_ ? prefix : MAXDET_;
    // zero rows [kept, 300) — disjoint from written ranks, no sync needed
    for (int i = kept * 6 + lane; i < MAXDET_ * 6; i += 64)
        out[(size_t)b * MAXDET_ * 6 + i] = 0.0f;
}

extern "C" void kernel_launch(void* const* d_in, const int* in_sizes, int n_in,
                              void* d_out, int out_size, void* d_ws, size_t ws_size,
                              hipStream_t stream) {
    const float* det = (const float*)d_in[0];
    float* out = (float*)d_out;
    char* ws = (char*)d_ws;

    u64* keys = (u64*)(ws + OFF_KEYS);
    u64* selk = (u64*)(ws + OFF_SELK);
    float4* obox4 = (float4*)(ws + OFF_OBOX);
    float* oar = (float*)(ws + OFF_OAR);
    float* pay = (float*)(ws + OFF_PAY);
    int* valid = (int*)(ws + OFF_VALID);
    u64* mask = (u64*)(ws + OFF_MASK);

    dim3 g1((N_ + K1_ROWS - 1) / K1_ROWS, B_);
    score_kernel<<<g1, 256, 0, stream>>>(det, keys);
    select_kernel<<<B_, 1024, 0, stream>>>(keys, selk);
    rank_kernel<<<B_ * 16, 64, 0, stream>>>(det, selk, obox4, oar, pay, valid);
    dim3 g4(TOPK_ / 16, B_);
    mask_kernel<<<g4, 256, 0, stream>>>(obox4, oar, mask);
    scan_kernel<<<B_, 64, 0, stream>>>(mask, valid, pay, out);
}

// Round 3
// 165.213 us; speedup vs baseline: 3.3020x; 1.8599x over previous
//
#include <hip/hip_runtime.h>
#include <stdint.h>

#define B_ 16
#define N_ 25200
#define NC_ 80
#define ROW_ 85
#define TOPK_ 1024
#define MAXDET_ 300
#define CONF_T 0.25f
#define IOU_T 0.45f
#define MAX_WH_ 4096.0f
#define NBINS_ 16384   /* top-14-bit histogram (key bits [50:64)) */
#define CBUF_CAP 4096

typedef unsigned long long u64;
typedef unsigned int u32;

// ws layout (bytes). T (transposed suppression matrix, 2 MB) ALIASES keys
// (3.2 MB): keys are dead after select_kernel, mask_kernel runs after it.
#define OFF_KEYS  0ull                      // 16*25200*8 = 3,225,600
#define OFF_T     0ull                      // 16*1024*16*8 = 2,097,152 (alias)
#define OFF_HIST  3225600ull                // 16*16384*4 = 1,048,576
#define OFF_SELK  4274176ull                // 16*1024*8  =   131,072
#define OFF_OBOX  4405248ull                // 16*1024*16 =   262,144
#define OFF_OAR   4667392ull                // 16*1024*4  =    65,536
#define OFF_PAY   4732928ull                // 16*1024*24 =   393,216
#define OFF_VALID 5126144ull                // 16*1024*4  =    65,536  -> end 5,191,680

// ---------------------------------------------------------------------------
// K1: float4-staged coalesced score computation + fused top-14-bit histogram.
// key = conf_bits<<32 | (0xFFFFFFFF - n)  (unique; desc order == lax.top_k)
// ---------------------------------------------------------------------------
#define K1_ROWS 128
__global__ void __launch_bounds__(256) score_kernel(const float* __restrict__ det,
                                                    u64* __restrict__ keys,
                                                    u32* __restrict__ hist) {
#pragma clang fp contract(off)
    __shared__ float s[K1_ROWS * ROW_];
    const int b = blockIdx.y;
    const int r0 = blockIdx.x * K1_ROWS;
    const int rows = min(K1_ROWS, N_ - r0);
    const int t = threadIdx.x;
    const float* src = det + ((size_t)b * N_ + r0) * ROW_;
    const int cnt = rows * ROW_;
    const int cnt4 = cnt >> 2;
    const float4* src4 = (const float4*)src;      // 16B-aligned: (b*N+r0)*85 ≡ 0 mod 4
    float4* s4 = (float4*)s;
    for (int i = t; i < cnt4; i += 256) s4[i] = src4[i];
    for (int i = (cnt4 << 2) + t; i < cnt; i += 256) s[i] = src[i];
    __syncthreads();

    u64 key = 0;
    float conf = 0.0f;
    const bool active = (t < rows);
    if (active) {
        const float* row = s + t * ROW_;
        float obj = row[4];
        float m = -1.0f;
#pragma unroll 8
        for (int c = 0; c < NC_; ++c) {
            float p = obj * row[5 + c];
            m = (p > m) ? p : m;
        }
        conf = (obj > CONF_T && m > CONF_T) ? m : 0.0f;
        int n = r0 + t;
        key = ((u64)__float_as_uint(conf) << 32) | (u32)(0xFFFFFFFFu - (u32)n);
        keys[(size_t)b * N_ + n] = key;
    }
    // histogram; wave-aggregate the (huge) conf==0 bin to avoid same-address
    // atomic serialization
    u64 zb = __ballot(active && conf == 0.0f);
    if (active) {
        if (conf != 0.0f)
            atomicAdd(&hist[b * NBINS_ + (u32)(key >> 50)], 1u);
        else if ((t & 63) == (__ffsll((long long)zb) - 1))
            atomicAdd(&hist[b * NBINS_], (u32)__popcll(zb));
    }
}

// ---------------------------------------------------------------------------
// K2: exact top-1024 select, one 1024-thr block per batch.
//  A: parallel suffix over 16384-bin global hist -> coarse cutoff CUT with
//     count(key>=CUT) in [1024, ~1400]
//  B: one global scan compacts keys>=CUT into LDS cbuf
//  C: 8 byte radix passes over cbuf (LDS atomics + wave-parallel digit scan)
//  D: gather exactly 1024 keys >= T into selk (unsorted)
// ---------------------------------------------------------------------------
__global__ void __launch_bounds__(1024) select_kernel(const u64* __restrict__ keys,
                                                      const u32* __restrict__ hist,
                                                      u64* __restrict__ selk) {
    const int b = blockIdx.x;
    const int t = threadIdx.x;
    __shared__ u32 suf[1024];
    __shared__ u64 cbuf[CBUF_CAP];
    __shared__ u32 hist256[256];
    __shared__ u64 s_prefix;
    __shared__ int s_k, s_cnt, s_cutd;

    const u64* bkeys = keys + (size_t)b * N_;
    const u32* bh = hist + b * NBINS_;

    // ---- A: chunk sums (16 bins/thread) + Hillis-Steele suffix scan ----
    u32 h[16];
    u32 csum = 0;
#pragma unroll
    for (int q = 0; q < 16; ++q) { h[q] = bh[t * 16 + q]; csum += h[q]; }
    suf[t] = csum;
    __syncthreads();
    for (int off = 1; off < 1024; off <<= 1) {
        u32 v = (t + off < 1024) ? suf[t + off] : 0;
        __syncthreads();
        suf[t] += v;
        __syncthreads();
    }
    {
        u32 mine = suf[t];
        u32 above = (t + 1 < 1024) ? suf[t + 1] : 0;
        if (mine >= (u32)TOPK_ && above < (u32)TOPK_) {
            // boundary chunk: walk its 16 bins high->low (register-resident)
            u32 cum = above;
            int cutd = t * 16;
            bool found = false;
#pragma unroll
            for (int q = 15; q >= 0; --q) {
                if (!found && cum + h[q] >= (u32)TOPK_) { cutd = t * 16 + q; found = true; }
                if (!found) cum += h[q];
            }
            s_cutd = cutd;
        }
    }
    __syncthreads();
    const u64 CUT = ((u64)(u32)s_cutd) << 50;

    // ---- B: compact keys >= CUT into LDS ----
    if (t == 0) s_cnt = 0;
    __syncthreads();
    for (int n = t; n < N_; n += 1024) {
        u64 key = bkeys[n];
        if (key >= CUT) {
            int pos = atomicAdd(&s_cnt, 1);
            if (pos < CBUF_CAP) cbuf[pos] = key;
        }
    }
    __syncthreads();
    const int cnt = min(s_cnt, CBUF_CAP);

    // ---- C: 8 radix passes entirely in LDS ----
    u64 prefix = 0;
    int k = TOPK_;
    for (int shift = 56; shift >= 0; shift -= 8) {
        if (t < 256) hist256[t] = 0;
        __syncthreads();
        for (int n = t; n < cnt; n += 1024) {
            u64 key = cbuf[n];
            if (shift == 56 || (key >> (shift + 8)) == prefix)
                atomicAdd(&hist256[(u32)(key >> shift) & 255u], 1u);
        }
        __syncthreads();
        if (t < 64) {   // wave 0: parallel digit suffix-scan, 4 bins/lane
            u32 b0 = hist256[t * 4 + 0], b1 = hist256[t * 4 + 1];
            u32 b2 = hist256[t * 4 + 2], b3 = hist256[t * 4 + 3];
            u32 sgrp = b0 + b1 + b2 + b3;
            u32 sufl = sgrp;
#pragma unroll
            for (int off = 1; off < 64; off <<= 1) {
                u32 vv = __shfl(sufl, t + off);
                sufl += (t + off < 64) ? vv : 0;
            }
            u32 A = sufl - sgrp;     // count in digits above this lane's group
            if (sufl >= (u32)k && A < (u32)k) {
                u32 cum = A;
                int d = t * 4;
                bool found = false;
                u32 hh0 = b0, hh1 = b1, hh2 = b2, hh3 = b3;
                if (!found && cum + hh3 >= (u32)k) { d = t * 4 + 3; found = true; }
                if (!found) { cum += hh3; if (cum + hh2 >= (u32)k) { d = t * 4 + 2; found = true; } }
                if (!found) { cum += hh2; if (cum + hh1 >= (u32)k) { d = t * 4 + 1; found = true; } }
                if (!found) { cum += hh1; if (cum + hh0 >= (u32)k) { d = t * 4 + 0; found = true; } }
                s_prefix = (prefix << 8) | (u64)d;
                s_k = k - (int)cum;
            }
        }
        __syncthreads();
        prefix = s_prefix;
        k = s_k;
        __syncthreads();
    }
    const u64 T64 = prefix;   // exact 1024th-largest key

    // ---- D: gather all keys >= T64 (exactly 1024, keys unique) ----
    if (t == 0) s_cnt = 0;
    __syncthreads();
    for (int n = t; n < cnt; n += 1024) {
        u64 key = cbuf[n];
        if (key >= T64) {
            int pos = atomicAdd(&s_cnt, 1);
            if (pos < TOPK_) selk[(size_t)b * TOPK_ + pos] = key;
        }
    }
}

// ---------------------------------------------------------------------------
// K3: rank the 1024 keys (brute force, 1 wave/block), gather rows, recompute
// cls/boxes with reference FP order, write into sorted slots.
// ---------------------------------------------------------------------------
__global__ void __launch_bounds__(64) rank_kernel(const float* __restrict__ det,
                                                  const u64* __restrict__ selk,
                                                  float4* __restrict__ obox4,
                                                  float* __restrict__ oar,
                                                  float* __restrict__ pay,
                                                  int* __restrict__ valid) {
#pragma clang fp contract(off)
    __shared__ u64 sk[TOPK_];
    const int b = blockIdx.x >> 4;
    const int chunk = blockIdx.x & 15;
    const int t = threadIdx.x;
    for (int i = t; i < TOPK_; i += 64) sk[i] = selk[(size_t)b * TOPK_ + i];
    __syncthreads();
    u64 myk = sk[chunk * 64 + t];
    int rank = 0;
#pragma unroll 8
    for (int i = 0; i < TOPK_; ++i) rank += (sk[i] > myk) ? 1 : 0;

    int n_idx = (int)(0xFFFFFFFFu - (u32)myk);
    float conf = __uint_as_float((u32)(myk >> 32));
    const float* row = det + ((size_t)b * N_ + n_idx) * ROW_;
    float xc = row[0], yc = row[1], w = row[2], h = row[3];
    float obj = row[4];
    float m = -1.0f;
    int cls = 0;
    for (int c = 0; c < NC_; ++c) {
        float p = obj * row[5 + c];
        if (p > m) { m = p; cls = c; }   // strict > == jnp.argmax first-max
    }
    float hw = w * 0.5f, hh = h * 0.5f;
    float x1 = xc - hw, y1 = yc - hh, x2 = xc + hw, y2 = yc + hh;
    float off = (float)cls * MAX_WH_;
    float X1 = x1 + off, Y1 = y1 + off, X2 = x2 + off, Y2 = y2 + off;
    float area = fmaxf(X2 - X1, 0.0f) * fmaxf(Y2 - Y1, 0.0f);

    size_t o = (size_t)b * TOPK_ + rank;
    obox4[o] = make_float4(X1, Y1, X2, Y2);
    oar[o] = area;
    float* p6 = pay + o * 6;
    p6[0] = x1; p6[1] = y1; p6[2] = x2; p6[3] = y2;
    p6[4] = conf; p6[5] = (float)cls;
    valid[o] = (conf > 0.0f) ? 1 : 0;
}

// ---------------------------------------------------------------------------
// K4: TRANSPOSED suppression matrix. T[j][w] bit r = row i=w*64+r suppresses
// column j:  (j > i) && (iou(i,j) > IOU_T).  Reference FP order:
// uni = ((area_i + area_j) - inter) + 1e-7; iou = inter/uni (IEEE div).
// ---------------------------------------------------------------------------
__global__ void __launch_bounds__(256) mask_kernel(const float4* __restrict__ obox4,
                                                   const float* __restrict__ oar,
                                                   u64* __restrict__ T) {
#pragma clang fp contract(off)
    __shared__ float4 sbox[TOPK_];
    __shared__ float sar[TOPK_];
    const int b = blockIdx.y;
    const int t = threadIdx.x;
    for (int i = t; i < TOPK_; i += 256) {
        sbox[i] = obox4[(size_t)b * TOPK_ + i];
        sar[i] = oar[(size_t)b * TOPK_ + i];
    }
    __syncthreads();
    const int j = blockIdx.x * 16 + (t >> 4);   // column
    const int w = t & 15;                       // row word
    float4 bj = sbox[j];
    float aj = sar[j];
    u64 m = 0;
#pragma unroll 4
    for (int jj = 0; jj < 64; ++jj) {
        int r = (jj + 5 * w) & 63;              // stagger LDS broadcast groups
        int i = (w << 6) | r;
        float4 bi = sbox[i];
        float ai = sar[i];
        float lx = fmaxf(bi.x, bj.x);
        float ly = fmaxf(bi.y, bj.y);
        float rx = fminf(bi.z, bj.z);
        float ry = fminf(bi.w, bj.w);
        float iw = fmaxf(rx - lx, 0.0f);
        float ih = fmaxf(ry - ly, 0.0f);
        float inter = iw * ih;
        float uni = ai + aj - inter + 1e-7f;
        bool sup = (inter / uni > IOU_T) && (j > i);
        m |= sup ? (1ull << r) : 0ull;
    }
    T[((size_t)b * TOPK_ + j) * 16 + w] = m;
}

// ---------------------------------------------------------------------------
// K5: word-parallel exact greedy scan, one wave per batch.
// Per 64-row word: exact ballot fixpoint (each round confirms >=1 row;
// typically 2-3 rounds). Cross-word suppression via 1 ballot per earlier
// word. Early termination once >=300 kept (later rows provably excluded:
// kept scores are descending, top_k is stable).
// ---------------------------------------------------------------------------
__global__ void __launch_bounds__(64) scan_kernel(const u64* __restrict__ T,
                                                  const int* __restrict__ valid,
                                                  const float* __restrict__ pay,
                                                  float* __restrict__ out) {
    const int b = blockIdx.x;
    const int lane = threadIdx.x;
    u64 kept[16];
    bool done = false;
    int total = 0;

#pragma unroll
    for (int sw = 0; sw < 16; ++sw) {
        if (done) { kept[sw] = 0; continue; }
        // lane's column j = sw*64+lane: contiguous 128B of T (words 0..15)
        const u64* col = T + ((size_t)(b * TOPK_ + sw * 64 + lane)) * 16;
        u64 tc[16];
#pragma unroll
        for (int q = 0; q < 8; ++q) {
            ulonglong2 v = reinterpret_cast<const ulonglong2*>(col)[q];
            tc[2 * q] = v.x;
            tc[2 * q + 1] = v.y;
        }
        int vint = valid[b * TOPK_ + sw * 64 + lane];
        u64 vw = __ballot(vint != 0);
        // incoming removals from earlier words' kept rows
        u64 rem_in = 0;
#pragma unroll
        for (int s = 0; s < 16; ++s) {
            if (s < sw) rem_in |= __ballot((kept[s] & tc[s]) != 0);
        }
        // within-word exact fixpoint. K=kept, R=removed/invalid, U=unresolved.
        // Lane l = column l: tc[sw] = rows (r<l) in this word that suppress l.
        u64 Td = tc[sw];
        u64 K = 0;
        u64 R = (~vw) | rem_in;
        u64 U = ~(K | R);
        int guard = 0;
        while (U && guard++ < 64) {
            u64 S = Td & (K | U);       // not-yet-ruled-out suppressors
            bool inU = ((U >> lane) & 1ull) != 0;
            u64 nK = __ballot(inU && (S == 0));
            u64 nR = __ballot(inU && ((S & K) != 0));
            K |= nK;
            R |= nR;
            U &= ~(nK | nR);
        }
        kept[sw] = K;
        total += __popcll(K);
        if (total >= MAXDET_) done = true;
    }

    // write kept rows (rank order), zero the tail
    int cum = 0;
#pragma unroll
    for (int w = 0; w < 16; ++w) {
        u64 aw = kept[w];
        bool bit = ((aw >> lane) & 1ull) != 0;
        int rank = cum + __popcll(aw & ((1ull << lane) - 1ull));
        if (bit && rank < MAXDET_) {
            const float* p6 = pay + ((size_t)(b * TOPK_ + w * 64 + lane)) * 6;
            float* o = out + ((size_t)(b * MAXDET_ + rank)) * 6;
            o[0] = p6[0]; o[1] = p6[1]; o[2] = p6[2];
            o[3] = p6[3]; o[4] = p6[4]; o[5] = p6[5];
        }
        cum += __popcll(aw);
    }
    int kept_n = cum < MAXDET_ ? cum : MAXDET_;
    for (int i = kept_n * 6 + lane; i < MAXDET_ * 6; i += 64)
        out[(size_t)b * MAXDET_ * 6 + i] = 0.0f;
}

extern "C" void kernel_launch(void* const* d_in, const int* in_sizes, int n_in,
                              void* d_out, int out_size, void* d_ws, size_t ws_size,
                              hipStream_t stream) {
    const float* det = (const float*)d_in[0];
    float* out = (float*)d_out;
    char* ws = (char*)d_ws;

    u64* keys = (u64*)(ws + OFF_KEYS);
    u64* T = (u64*)(ws + OFF_T);       // aliases keys (dead before mask runs)
    u32* hist = (u32*)(ws + OFF_HIST);
    u64* selk = (u64*)(ws + OFF_SELK);
    float4* obox4 = (float4*)(ws + OFF_OBOX);
    float* oar = (float*)(ws + OFF_OAR);
    float* pay = (float*)(ws + OFF_PAY);
    int* valid = (int*)(ws + OFF_VALID);

    hipMemsetAsync(hist, 0, (size_t)B_ * NBINS_ * sizeof(u32), stream);
    dim3 g1((N_ + K1_ROWS - 1) / K1_ROWS, B_);
    score_kernel<<<g1, 256, 0, stream>>>(det, keys, hist);
    select_kernel<<<B_, 1024, 0, stream>>>(keys, hist, selk);
    rank_kernel<<<B_ * 16, 64, 0, stream>>>(det, selk, obox4, oar, pay, valid);
    dim3 g4(TOPK_ / 16, B_);
    mask_kernel<<<g4, 256, 0, stream>>>(obox4, oar, T);
    scan_kernel<<<B_, 64, 0, stream>>>(T, valid, pay, out);
}

// Round 4
// 160.715 us; speedup vs baseline: 3.3945x; 1.0280x over previous
//
#include <hip/hip_runtime.h>
#include <stdint.h>

#define B_ 16
#define N_ 25200
#define NC_ 80
#define ROW_ 85
#define TOPK_ 1024
#define MAXDET_ 300
#define CONF_T 0.25f
#define IOU_T 0.45f
#define MAX_WH_ 4096.0f
#define NBINS_ 16384   /* top-14-bit histogram (key bits [50:64)) */
#define CBUF_CAP 4096

typedef unsigned long long u64;
typedef unsigned int u32;

// ws layout (bytes). T (transposed suppression matrix, 2 MB) ALIASES keys
// (3.2 MB): keys are dead after select_kernel, mask_kernel runs after it.
#define OFF_KEYS  0ull                      // 16*25200*8 = 3,225,600
#define OFF_T     0ull                      // 16*1024*16*8 = 2,097,152 (alias)
#define OFF_HIST  3225600ull                // 16*16384*4 = 1,048,576
#define OFF_SELK  4274176ull                // 16*1024*8  =   131,072
#define OFF_OBOX  4405248ull                // 16*1024*16 =   262,144
#define OFF_OAR   4667392ull                // 16*1024*4  =    65,536
#define OFF_PAY   4732928ull                // 16*1024*24 =   393,216
#define OFF_VALID 5126144ull                // 16*1024*4  =    65,536  -> end 5,191,680

// ---------------------------------------------------------------------------
// K1 v2: 64 rows/block (LDS 21.7KB -> 7 blocks/CU), float4-staged, compute
// uses ALL 256 threads: 4 lanes per row, 20 classes each, fmax-combined via
// shfl_xor (same 80 identically-rounded products -> bit-identical max).
// key = conf_bits<<32 | (0xFFFFFFFF - n)  (unique; desc order == lax.top_k)
// ---------------------------------------------------------------------------
#define K1_ROWS 64
__global__ void __launch_bounds__(256) score_kernel(const float* __restrict__ det,
                                                    u64* __restrict__ keys,
                                                    u32* __restrict__ hist) {
#pragma clang fp contract(off)
    __shared__ float s[K1_ROWS * ROW_];           // 21,760 B
    const int b = blockIdx.y;
    const int r0 = blockIdx.x * K1_ROWS;
    const int rows = min(K1_ROWS, N_ - r0);
    const int t = threadIdx.x;
    const float* src = det + ((size_t)b * N_ + r0) * ROW_;
    const int cnt = rows * ROW_;                  // multiple of 4 (64|48 rows)
    const int cnt4 = cnt >> 2;
    const float4* src4 = (const float4*)src;      // (b*N+r0)*85 ≡ 0 mod 4
    float4* s4 = (float4*)s;
    for (int i = t; i < cnt4; i += 256) s4[i] = src4[i];
    for (int i = (cnt4 << 2) + t; i < cnt; i += 256) s[i] = src[i];
    __syncthreads();

    const int row = t >> 2;
    const int h = t & 3;
    const bool rv = (row < rows);
    float m = -1.0f;
    float obj = 0.0f;
    if (rv) {
        const float* rp = s + row * ROW_;
        obj = rp[4];
#pragma unroll
        for (int c = 0; c < 20; ++c) {
            float p = obj * rp[5 + h * 20 + c];
            m = (p > m) ? p : m;
        }
    }
    m = fmaxf(m, __shfl_xor(m, 1));
    m = fmaxf(m, __shfl_xor(m, 2));
    float conf = (rv && obj > CONF_T && m > CONF_T) ? m : 0.0f;
    u64 key = ((u64)__float_as_uint(conf) << 32) |
              (u32)(0xFFFFFFFFu - (u32)(r0 + row));
    if (rv && h == 0) keys[(size_t)b * N_ + r0 + row] = key;

    // histogram; wave-aggregate the (huge) conf==0 bin
    u64 zb = __ballot(rv && h == 0 && conf == 0.0f);
    if (rv && h == 0) {
        if (conf != 0.0f)
            atomicAdd(&hist[b * NBINS_ + (u32)(key >> 50)], 1u);
        else if ((t & 63) == (__ffsll((long long)zb) - 1))
            atomicAdd(&hist[b * NBINS_], (u32)__popcll(zb));
    }
}

// ---------------------------------------------------------------------------
// K2: exact top-1024 select, one 1024-thr block per batch.
//  A: suffix scan of 16384-bin hist (wave shfl + 1 LDS combine) -> coarse CUT
//  B: one global scan (4x unrolled) compacts keys>=CUT into LDS cbuf
//  C: 8 byte radix passes over cbuf (LDS atomics + wave-parallel digit scan)
//  D: gather exactly 1024 keys >= T into selk (unsorted)
// ---------------------------------------------------------------------------
__global__ void __launch_bounds__(1024) select_kernel(const u64* __restrict__ keys,
                                                      const u32* __restrict__ hist,
                                                      u64* __restrict__ selk) {
    const int b = blockIdx.x;
    const int t = threadIdx.x;
    const int lane = t & 63;
    const int wid = t >> 6;
    __shared__ u32 wtot[16];
    __shared__ u64 cbuf[CBUF_CAP];
    __shared__ u32 hist256[256];
    __shared__ u64 s_prefix;
    __shared__ int s_k, s_cnt, s_cutd;

    const u64* bkeys = keys + (size_t)b * N_;
    const u32* bh = hist + b * NBINS_;

    // ---- A: 16 bins/thread; wave suffix-scan + cross-wave combine ----
    u32 h[16];
    u32 csum = 0;
#pragma unroll
    for (int q = 0; q < 16; ++q) { h[q] = bh[t * 16 + q]; csum += h[q]; }
    u32 suf = csum;
#pragma unroll
    for (int off = 1; off < 64; off <<= 1) {
        u32 v = __shfl_down(suf, off);
        if (lane + off < 64) suf += v;
    }
    if (lane == 0) wtot[wid] = suf;     // wave total (suffix at lane 0)
    __syncthreads();
    u32 hi = 0;
    for (int w = wid + 1; w < 16; ++w) hi += wtot[w];
    u32 above = (suf - csum) + hi;      // sum over threads strictly after t
    u32 incl = above + csum;
    if (incl >= (u32)TOPK_ && above < (u32)TOPK_) {
        u32 cum = above;
        int cutd = t * 16;
        bool found = false;
#pragma unroll
        for (int q = 15; q >= 0; --q) {
            if (!found && cum + h[q] >= (u32)TOPK_) { cutd = t * 16 + q; found = true; }
            if (!found) cum += h[q];
        }
        s_cutd = cutd;
    }
    __syncthreads();
    const u64 CUT = ((u64)(u32)s_cutd) << 50;

    // ---- B: compact keys >= CUT into LDS (4x unrolled for MLP) ----
    if (t == 0) s_cnt = 0;
    __syncthreads();
    int n = t;
    for (; n + 3 * 1024 < N_; n += 4096) {
        u64 k0 = bkeys[n];
        u64 k1 = bkeys[n + 1024];
        u64 k2 = bkeys[n + 2048];
        u64 k3 = bkeys[n + 3072];
        if (k0 >= CUT) { int p = atomicAdd(&s_cnt, 1); if (p < CBUF_CAP) cbuf[p] = k0; }
        if (k1 >= CUT) { int p = atomicAdd(&s_cnt, 1); if (p < CBUF_CAP) cbuf[p] = k1; }
        if (k2 >= CUT) { int p = atomicAdd(&s_cnt, 1); if (p < CBUF_CAP) cbuf[p] = k2; }
        if (k3 >= CUT) { int p = atomicAdd(&s_cnt, 1); if (p < CBUF_CAP) cbuf[p] = k3; }
    }
    for (; n < N_; n += 1024) {
        u64 key = bkeys[n];
        if (key >= CUT) { int p = atomicAdd(&s_cnt, 1); if (p < CBUF_CAP) cbuf[p] = key; }
    }
    __syncthreads();
    const int cnt = min(s_cnt, CBUF_CAP);

    // ---- C: 8 radix passes entirely in LDS ----
    u64 prefix = 0;
    int k = TOPK_;
    for (int shift = 56; shift >= 0; shift -= 8) {
        if (t < 256) hist256[t] = 0;
        __syncthreads();
        for (int nn = t; nn < cnt; nn += 1024) {
            u64 key = cbuf[nn];
            if (shift == 56 || (key >> (shift + 8)) == prefix)
                atomicAdd(&hist256[(u32)(key >> shift) & 255u], 1u);
        }
        __syncthreads();
        if (t < 64) {   // wave 0: parallel digit suffix-scan, 4 bins/lane
            u32 b0 = hist256[t * 4 + 0], b1 = hist256[t * 4 + 1];
            u32 b2 = hist256[t * 4 + 2], b3 = hist256[t * 4 + 3];
            u32 sgrp = b0 + b1 + b2 + b3;
            u32 sufl = sgrp;
#pragma unroll
            for (int off = 1; off < 64; off <<= 1) {
                u32 vv = __shfl(sufl, t + off);
                sufl += (t + off < 64) ? vv : 0;
            }
            u32 A = sufl - sgrp;
            if (sufl >= (u32)k && A < (u32)k) {
                u32 cum = A;
                int d = t * 4;
                bool found = false;
                if (!found && cum + b3 >= (u32)k) { d = t * 4 + 3; found = true; }
                if (!found) { cum += b3; if (cum + b2 >= (u32)k) { d = t * 4 + 2; found = true; } }
                if (!found) { cum += b2; if (cum + b1 >= (u32)k) { d = t * 4 + 1; found = true; } }
                if (!found) { cum += b1; if (cum + b0 >= (u32)k) { d = t * 4 + 0; found = true; } }
                s_prefix = (prefix << 8) | (u64)d;
                s_k = k - (int)cum;
            }
        }
        __syncthreads();
        prefix = s_prefix;
        k = s_k;
        __syncthreads();
    }
    const u64 T64 = prefix;   // exact 1024th-largest key

    // ---- D: gather all keys >= T64 (exactly 1024, keys unique) ----
    if (t == 0) s_cnt = 0;
    __syncthreads();
    for (int nn = t; nn < cnt; nn += 1024) {
        u64 key = cbuf[nn];
        if (key >= T64) {
            int pos = atomicAdd(&s_cnt, 1);
            if (pos < TOPK_) selk[(size_t)b * TOPK_ + pos] = key;
        }
    }
}

// ---------------------------------------------------------------------------
// K3: rank the 1024 keys (brute force, 1 wave/block), gather rows, recompute
// cls/boxes with reference FP order, write into sorted slots.
// ---------------------------------------------------------------------------
__global__ void __launch_bounds__(64) rank_kernel(const float* __restrict__ det,
                                                  const u64* __restrict__ selk,
                                                  float4* __restrict__ obox4,
                                                  float* __restrict__ oar,
                                                  float* __restrict__ pay,
                                                  int* __restrict__ valid) {
#pragma clang fp contract(off)
    __shared__ u64 sk[TOPK_];
    const int b = blockIdx.x >> 4;
    const int chunk = blockIdx.x & 15;
    const int t = threadIdx.x;
    for (int i = t; i < TOPK_; i += 64) sk[i] = selk[(size_t)b * TOPK_ + i];
    __syncthreads();
    u64 myk = sk[chunk * 64 + t];
    int rank = 0;
#pragma unroll 8
    for (int i = 0; i < TOPK_; ++i) rank += (sk[i] > myk) ? 1 : 0;

    int n_idx = (int)(0xFFFFFFFFu - (u32)myk);
    float conf = __uint_as_float((u32)(myk >> 32));
    const float* row = det + ((size_t)b * N_ + n_idx) * ROW_;
    float xc = row[0], yc = row[1], w = row[2], h = row[3];
    float obj = row[4];
    float m = -1.0f;
    int cls = 0;
    for (int c = 0; c < NC_; ++c) {
        float p = obj * row[5 + c];
        if (p > m) { m = p; cls = c; }   // strict > == jnp.argmax first-max
    }
    float hw = w * 0.5f, hh = h * 0.5f;
    float x1 = xc - hw, y1 = yc - hh, x2 = xc + hw, y2 = yc + hh;
    float off = (float)cls * MAX_WH_;
    float X1 = x1 + off, Y1 = y1 + off, X2 = x2 + off, Y2 = y2 + off;
    float area = fmaxf(X2 - X1, 0.0f) * fmaxf(Y2 - Y1, 0.0f);

    size_t o = (size_t)b * TOPK_ + rank;
    obox4[o] = make_float4(X1, Y1, X2, Y2);
    oar[o] = area;
    float* p6 = pay + o * 6;
    p6[0] = x1; p6[1] = y1; p6[2] = x2; p6[3] = y2;
    p6[4] = conf; p6[5] = (float)cls;
    valid[o] = (conf > 0.0f) ? 1 : 0;
}

// ---------------------------------------------------------------------------
// K4: TRANSPOSED suppression matrix. T[j][w] bit r = row i=w*64+r suppresses
// column j:  (j > i) && (iou(i,j) > IOU_T).  Reference FP order:
// uni = ((area_i + area_j) - inter) + 1e-7; iou = inter/uni (IEEE div).
// ---------------------------------------------------------------------------
__global__ void __launch_bounds__(256) mask_kernel(const float4* __restrict__ obox4,
                                                   const float* __restrict__ oar,
                                                   u64* __restrict__ T) {
#pragma clang fp contract(off)
    __shared__ float4 sbox[TOPK_];
    __shared__ float sar[TOPK_];
    const int b = blockIdx.y;
    const int t = threadIdx.x;
    for (int i = t; i < TOPK_; i += 256) {
        sbox[i] = obox4[(size_t)b * TOPK_ + i];
        sar[i] = oar[(size_t)b * TOPK_ + i];
    }
    __syncthreads();
    const int j = blockIdx.x * 16 + (t >> 4);   // column
    const int w = t & 15;                       // row word
    float4 bj = sbox[j];
    float aj = sar[j];
    u64 m = 0;
#pragma unroll 4
    for (int jj = 0; jj < 64; ++jj) {
        int r = (jj + 5 * w) & 63;              // stagger LDS broadcast groups
        int i = (w << 6) | r;
        float4 bi = sbox[i];
        float ai = sar[i];
        float lx = fmaxf(bi.x, bj.x);
        float ly = fmaxf(bi.y, bj.y);
        float rx = fminf(bi.z, bj.z);
        float ry = fminf(bi.w, bj.w);
        float iw = fmaxf(rx - lx, 0.0f);
        float ih = fmaxf(ry - ly, 0.0f);
        float inter = iw * ih;
        float uni = ai + aj - inter + 1e-7f;
        bool sup = (inter / uni > IOU_T) && (j > i);
        m |= sup ? (1ull << r) : 0ull;
    }
    T[((size_t)b * TOPK_ + j) * 16 + w] = m;
}

// ---------------------------------------------------------------------------
// K5: word-parallel exact greedy scan, one wave per batch.
// Per 64-row word: exact ballot fixpoint (>=1 row resolved per round).
// Cross-word suppression via 1 ballot per earlier word. Early termination
// once >=300 kept (kept scores descending, top_k stable).
// ---------------------------------------------------------------------------
__global__ void __launch_bounds__(64) scan_kernel(const u64* __restrict__ T,
                                                  const int* __restrict__ valid,
                                                  const float* __restrict__ pay,
                                                  float* __restrict__ out) {
    const int b = blockIdx.x;
    const int lane = threadIdx.x;
    u64 kept[16];
    bool done = false;
    int total = 0;

#pragma unroll
    for (int sw = 0; sw < 16; ++sw) {
        if (done) { kept[sw] = 0; continue; }
        const u64* col = T + ((size_t)(b * TOPK_ + sw * 64 + lane)) * 16;
        u64 tc[16];
#pragma unroll
        for (int q = 0; q < 8; ++q) {
            ulonglong2 v = reinterpret_cast<const ulonglong2*>(col)[q];
            tc[2 * q] = v.x;
            tc[2 * q + 1] = v.y;
        }
        int vint = valid[b * TOPK_ + sw * 64 + lane];
        u64 vw = __ballot(vint != 0);
        u64 rem_in = 0;
#pragma unroll
        for (int s = 0; s < 16; ++s) {
            if (s < sw) rem_in |= __ballot((kept[s] & tc[s]) != 0);
        }
        u64 Td = tc[sw];
        u64 K = 0;
        u64 R = (~vw) | rem_in;
        u64 U = ~(K | R);
        int guard = 0;
        while (U && guard++ < 64) {
            u64 S = Td & (K | U);
            bool inU = ((U >> lane) & 1ull) != 0;
            u64 nK = __ballot(inU && (S == 0));
            u64 nR = __ballot(inU && ((S & K) != 0));
            K |= nK;
            R |= nR;
            U &= ~(nK | nR);
        }
        kept[sw] = K;
        total += __popcll(K);
        if (total >= MAXDET_) done = true;
    }

    int cum = 0;
#pragma unroll
    for (int w = 0; w < 16; ++w) {
        u64 aw = kept[w];
        bool bit = ((aw >> lane) & 1ull) != 0;
        int rank = cum + __popcll(aw & ((1ull << lane) - 1ull));
        if (bit && rank < MAXDET_) {
            const float* p6 = pay + ((size_t)(b * TOPK_ + w * 64 + lane)) * 6;
            float* o = out + ((size_t)(b * MAXDET_ + rank)) * 6;
            o[0] = p6[0]; o[1] = p6[1]; o[2] = p6[2];
            o[3] = p6[3]; o[4] = p6[4]; o[5] = p6[5];
        }
        cum += __popcll(aw);
    }
    int kept_n = cum < MAXDET_ ? cum : MAXDET_;
    for (int i = kept_n * 6 + lane; i < MAXDET_ * 6; i += 64)
        out[(size_t)b * MAXDET_ * 6 + i] = 0.0f;
}

extern "C" void kernel_launch(void* const* d_in, const int* in_sizes, int n_in,
                              void* d_out, int out_size, void* d_ws, size_t ws_size,
                              hipStream_t stream) {
    const float* det = (const float*)d_in[0];
    float* out = (float*)d_out;
    char* ws = (char*)d_ws;

    u64* keys = (u64*)(ws + OFF_KEYS);
    u64* T = (u64*)(ws + OFF_T);       // aliases keys (dead before mask runs)
    u32* hist = (u32*)(ws + OFF_HIST);
    u64* selk = (u64*)(ws + OFF_SELK);
    float4* obox4 = (float4*)(ws + OFF_OBOX);
    float* oar = (float*)(ws + OFF_OAR);
    float* pay = (float*)(ws + OFF_PAY);
    int* valid = (int*)(ws + OFF_VALID);

    hipMemsetAsync(hist, 0, (size_t)B_ * NBINS_ * sizeof(u32), stream);
    dim3 g1((N_ + K1_ROWS - 1) / K1_ROWS, B_);
    score_kernel<<<g1, 256, 0, stream>>>(det, keys, hist);
    select_kernel<<<B_, 1024, 0, stream>>>(keys, hist, selk);
    rank_kernel<<<B_ * 16, 64, 0, stream>>>(det, selk, obox4, oar, pay, valid);
    dim3 g4(TOPK_ / 16, B_);
    mask_kernel<<<g4, 256, 0, stream>>>(obox4, oar, T);
    scan_kernel<<<B_, 64, 0, stream>>>(T, valid, pay, out);
}

// Round 6
// 135.817 us; speedup vs baseline: 4.0167x; 1.1833x over previous
//
#include <hip/hip_runtime.h>
#include <stdint.h>

#define B_ 16
#define N_ 25200
#define NC_ 80
#define ROW_ 85
#define TOPK_ 1024
#define MAXDET_ 300
#define CONF_T 0.25f
#define IOU_T 0.45f
#define MAX_WH_ 4096.0f
#define NBINS_ 16384   /* top-14-bit histogram (key bits [50:64)) */
#define CBUF_CAP 4096

typedef unsigned long long u64;
typedef unsigned int u32;

// ws layout (bytes). T (transposed suppression matrix, 2 MB) ALIASES keys
// (3.2 MB): keys are dead after select_kernel, mask_kernel runs after it.
#define OFF_KEYS  0ull                      // 16*25200*8 = 3,225,600
#define OFF_T     0ull                      // 16*1024*16*8 = 2,097,152 (alias)
#define OFF_HIST  3225600ull                // 16*16384*4 = 1,048,576
#define OFF_SELK  4274176ull                // 16*1024*8  =   131,072
#define OFF_OBOX  4405248ull                // 16*1024*16 =   262,144
#define OFF_OAR   4667392ull                // 16*1024*4  =    65,536
#define OFF_PAY   4732928ull                // 16*1024*24 =   393,216
#define OFF_VALID 5126144ull                // 16*1024*4  =    65,536  -> end 5,191,680

// ---------------------------------------------------------------------------
// K1 v4: persistent blocks + double-buffered global_load_lds (width 16) DMA.
// 64-row tiles (1360 float4). Each buffer is padded to the full 24-slot span
// (1536 float4) so EVERY slot's 64-lane write lands in-bounds — this fixes
// R5's bug where slot 21's tail lanes overflowed into the other buffer and
// raced with its staging DMA. Per wave exactly 6 loads/tile -> vmcnt(6)
// after issuing the NEXT tile's loads guarantees the CURRENT tile is
// resident while the prefetch stays in flight (counted-vmcnt pattern).
// Raw s_barrier (not __syncthreads) so the prefetch isn't drained.
// key = conf_bits<<32 | (0xFFFFFFFF - n)  (unique; desc order == lax.top_k)
// ---------------------------------------------------------------------------
#define K1_ROWS 64
#define K1_TPB  ((N_ + K1_ROWS - 1) / K1_ROWS)    /* 394 tiles per batch  */
#define K1_TILES (K1_TPB * B_)                    /* 6304 tiles total     */
#define K1_GRID 768                               /* 3 blocks/CU x 256 CU */
#define K1_F4   ((K1_ROWS * ROW_) / 4)            /* 1360 live float4/tile */
#define K1_SLOTS 24                               /* 6 per wave x 4 waves  */
#define K1_BUF_F4 (K1_SLOTS * 64)                 /* 1536 float4 buffer    */

__device__ __forceinline__ void k1_stage(const float4* __restrict__ src4, int cnt4,
                                         float4* buf, int wid, int lane) {
#pragma unroll
    for (int k = 0; k < 6; ++k) {
        const int s = k * 4 + wid;                 // slot 0..23
        const int f = s * 64 + lane;
        const float4* g = src4 + min(f, cnt4 - 1); // clamp: never read past det
        float4* l = buf + s * 64;                  // wave-uniform, in-bounds
        __builtin_amdgcn_global_load_lds(
            (const __attribute__((address_space(1))) void*)g,
            (__attribute__((address_space(3))) void*)l, 16, 0, 0);
    }
}

__global__ void __launch_bounds__(256) score_kernel(const float* __restrict__ det,
                                                    u64* __restrict__ keys,
                                                    u32* __restrict__ hist) {
#pragma clang fp contract(off)
    __shared__ float4 sbuf[2 * K1_BUF_F4];         // 49,152 B -> 3 blocks/CU
    const int t = threadIdx.x;
    const int wid = t >> 6;
    const int lane = t & 63;

    int tid = blockIdx.x;
    // prologue: stage first tile into buf 0
    {
        const int b0 = tid / K1_TPB, tk0 = tid % K1_TPB;
        const int r00 = tk0 * K1_ROWS;
        const int rows0 = min(K1_ROWS, N_ - r00);
        const float4* src4 = (const float4*)(det + ((size_t)b0 * N_ + r00) * ROW_);
        k1_stage(src4, rows0 * ROW_ / 4, &sbuf[0], wid, lane);
    }
    int p = 0;
    while (tid < K1_TILES) {
        const int b = tid / K1_TPB, tk = tid % K1_TPB;
        const int r0 = tk * K1_ROWS;
        const int rows = min(K1_ROWS, N_ - r0);
        const int next = tid + K1_GRID;
        const bool has_next = (next < K1_TILES);
        if (has_next) {
            const int nb = next / K1_TPB, ntk = next % K1_TPB;
            const int nr0 = ntk * K1_ROWS;
            const int nrows = min(K1_ROWS, N_ - nr0);
            const float4* nsrc4 = (const float4*)(det + ((size_t)nb * N_ + nr0) * ROW_);
            k1_stage(nsrc4, nrows * ROW_ / 4, &sbuf[(1 - p) * K1_BUF_F4], wid, lane);
            asm volatile("s_waitcnt vmcnt(6)" ::: "memory");  // current tile done
        } else {
            asm volatile("s_waitcnt vmcnt(0)" ::: "memory");
        }
        __builtin_amdgcn_sched_barrier(0);         // nothing hoists above the wait
        __builtin_amdgcn_s_barrier();              // raw barrier: keep prefetch alive

        // compute on buf[p]: 4 lanes/row, 20 classes each, shfl-combined max
        const float* sp = (const float*)&sbuf[p * K1_BUF_F4];
        const int row = t >> 2;
        const int h = t & 3;
        const bool rv = (row < rows);
        float m = -1.0f;
        float obj = 0.0f;
        if (rv) {
            const float* rp = sp + row * ROW_;
            obj = rp[4];
#pragma unroll
            for (int c = 0; c < 20; ++c) {
                float pr = obj * rp[5 + h * 20 + c];
                m = (pr > m) ? pr : m;
            }
        }
        m = fmaxf(m, __shfl_xor(m, 1));
        m = fmaxf(m, __shfl_xor(m, 2));
        float conf = (rv && obj > CONF_T && m > CONF_T) ? m : 0.0f;
        u64 key = ((u64)__float_as_uint(conf) << 32) |
                  (u32)(0xFFFFFFFFu - (u32)(r0 + row));
        if (rv && h == 0) keys[(size_t)b * N_ + r0 + row] = key;

        u64 zb = __ballot(rv && h == 0 && conf == 0.0f);
        if (rv && h == 0) {
            if (conf != 0.0f)
                atomicAdd(&hist[b * NBINS_ + (u32)(key >> 50)], 1u);
            else if ((t & 63) == (__ffsll((long long)zb) - 1))
                atomicAdd(&hist[b * NBINS_], (u32)__popcll(zb));
        }
        __builtin_amdgcn_s_barrier();  // all reads of buf[p] done before re-stage
        p ^= 1;
        tid = next;
    }
}

// ---------------------------------------------------------------------------
// K2: exact top-1024 select, one 1024-thr block per batch.
//  A: suffix scan of 16384-bin hist (wave shfl + 1 LDS combine) -> coarse CUT
//  B: one global scan (4x unrolled) compacts keys>=CUT into LDS cbuf
//  C: 8 byte radix passes over cbuf (LDS atomics + wave-parallel digit scan)
//  D: gather exactly 1024 keys >= T into selk (unsorted)
// ---------------------------------------------------------------------------
__global__ void __launch_bounds__(1024) select_kernel(const u64* __restrict__ keys,
                                                      const u32* __restrict__ hist,
                                                      u64* __restrict__ selk) {
    const int b = blockIdx.x;
    const int t = threadIdx.x;
    const int lane = t & 63;
    const int wid = t >> 6;
    __shared__ u32 wtot[16];
    __shared__ u64 cbuf[CBUF_CAP];
    __shared__ u32 hist256[256];
    __shared__ u64 s_prefix;
    __shared__ int s_k, s_cnt, s_cutd;

    const u64* bkeys = keys + (size_t)b * N_;
    const u32* bh = hist + b * NBINS_;

    // ---- A: 16 bins/thread; wave suffix-scan + cross-wave combine ----
    u32 h[16];
    u32 csum = 0;
#pragma unroll
    for (int q = 0; q < 16; ++q) { h[q] = bh[t * 16 + q]; csum += h[q]; }
    u32 suf = csum;
#pragma unroll
    for (int off = 1; off < 64; off <<= 1) {
        u32 v = __shfl_down(suf, off);
        if (lane + off < 64) suf += v;
    }
    if (lane == 0) wtot[wid] = suf;     // wave total (suffix at lane 0)
    __syncthreads();
    u32 hi = 0;
    for (int w = wid + 1; w < 16; ++w) hi += wtot[w];
    u32 above = (suf - csum) + hi;      // sum over threads strictly after t
    u32 incl = above + csum;
    if (incl >= (u32)TOPK_ && above < (u32)TOPK_) {
        u32 cum = above;
        int cutd = t * 16;
        bool found = false;
#pragma unroll
        for (int q = 15; q >= 0; --q) {
            if (!found && cum + h[q] >= (u32)TOPK_) { cutd = t * 16 + q; found = true; }
            if (!found) cum += h[q];
        }
        s_cutd = cutd;
    }
    __syncthreads();
    const u64 CUT = ((u64)(u32)s_cutd) << 50;

    // ---- B: compact keys >= CUT into LDS (4x unrolled for MLP) ----
    if (t == 0) s_cnt = 0;
    __syncthreads();
    int n = t;
    for (; n + 3 * 1024 < N_; n += 4096) {
        u64 k0 = bkeys[n];
        u64 k1 = bkeys[n + 1024];
        u64 k2 = bkeys[n + 2048];
        u64 k3 = bkeys[n + 3072];
        if (k0 >= CUT) { int p = atomicAdd(&s_cnt, 1); if (p < CBUF_CAP) cbuf[p] = k0; }
        if (k1 >= CUT) { int p = atomicAdd(&s_cnt, 1); if (p < CBUF_CAP) cbuf[p] = k1; }
        if (k2 >= CUT) { int p = atomicAdd(&s_cnt, 1); if (p < CBUF_CAP) cbuf[p] = k2; }
        if (k3 >= CUT) { int p = atomicAdd(&s_cnt, 1); if (p < CBUF_CAP) cbuf[p] = k3; }
    }
    for (; n < N_; n += 1024) {
        u64 key = bkeys[n];
        if (key >= CUT) { int p = atomicAdd(&s_cnt, 1); if (p < CBUF_CAP) cbuf[p] = key; }
    }
    __syncthreads();
    const int cnt = min(s_cnt, CBUF_CAP);

    // ---- C: 8 radix passes entirely in LDS ----
    u64 prefix = 0;
    int k = TOPK_;
    for (int shift = 56; shift >= 0; shift -= 8) {
        if (t < 256) hist256[t] = 0;
        __syncthreads();
        for (int nn = t; nn < cnt; nn += 1024) {
            u64 key = cbuf[nn];
            if (shift == 56 || (key >> (shift + 8)) == prefix)
                atomicAdd(&hist256[(u32)(key >> shift) & 255u], 1u);
        }
        __syncthreads();
        if (t < 64) {   // wave 0: parallel digit suffix-scan, 4 bins/lane
            u32 b0 = hist256[t * 4 + 0], b1 = hist256[t * 4 + 1];
            u32 b2 = hist256[t * 4 + 2], b3 = hist256[t * 4 + 3];
            u32 sgrp = b0 + b1 + b2 + b3;
            u32 sufl = sgrp;
#pragma unroll
            for (int off = 1; off < 64; off <<= 1) {
                u32 vv = __shfl(sufl, t + off);
                sufl += (t + off < 64) ? vv : 0;
            }
            u32 A = sufl - sgrp;
            if (sufl >= (u32)k && A < (u32)k) {
                u32 cum = A;
                int d = t * 4;
                bool found = false;
                if (!found && cum + b3 >= (u32)k) { d = t * 4 + 3; found = true; }
                if (!found) { cum += b3; if (cum + b2 >= (u32)k) { d = t * 4 + 2; found = true; } }
                if (!found) { cum += b2; if (cum + b1 >= (u32)k) { d = t * 4 + 1; found = true; } }
                if (!found) { cum += b1; if (cum + b0 >= (u32)k) { d = t * 4 + 0; found = true; } }
                s_prefix = (prefix << 8) | (u64)d;
                s_k = k - (int)cum;
            }
        }
        __syncthreads();
        prefix = s_prefix;
        k = s_k;
        __syncthreads();
    }
    const u64 T64 = prefix;   // exact 1024th-largest key

    // ---- D: gather all keys >= T64 (exactly 1024, keys unique) ----
    if (t == 0) s_cnt = 0;
    __syncthreads();
    for (int nn = t; nn < cnt; nn += 1024) {
        u64 key = cbuf[nn];
        if (key >= T64) {
            int pos = atomicAdd(&s_cnt, 1);
            if (pos < TOPK_) selk[(size_t)b * TOPK_ + pos] = key;
        }
    }
}

// ---------------------------------------------------------------------------
// K3: rank the 1024 keys (brute force, 1 wave/block), gather rows, recompute
// cls/boxes with reference FP order, write into sorted slots.
// ---------------------------------------------------------------------------
__global__ void __launch_bounds__(64) rank_kernel(const float* __restrict__ det,
                                                  const u64* __restrict__ selk,
                                                  float4* __restrict__ obox4,
                                                  float* __restrict__ oar,
                                                  float* __restrict__ pay,
                                                  int* __restrict__ valid) {
#pragma clang fp contract(off)
    __shared__ u64 sk[TOPK_];
    const int b = blockIdx.x >> 4;
    const int chunk = blockIdx.x & 15;
    const int t = threadIdx.x;
    for (int i = t; i < TOPK_; i += 64) sk[i] = selk[(size_t)b * TOPK_ + i];
    __syncthreads();
    u64 myk = sk[chunk * 64 + t];
    int rank = 0;
#pragma unroll 8
    for (int i = 0; i < TOPK_; ++i) rank += (sk[i] > myk) ? 1 : 0;

    int n_idx = (int)(0xFFFFFFFFu - (u32)myk);
    float conf = __uint_as_float((u32)(myk >> 32));
    const float* row = det + ((size_t)b * N_ + n_idx) * ROW_;
    float xc = row[0], yc = row[1], w = row[2], h = row[3];
    float obj = row[4];
    float m = -1.0f;
    int cls = 0;
    for (int c = 0; c < NC_; ++c) {
        float p = obj * row[5 + c];
        if (p > m) { m = p; cls = c; }   // strict > == jnp.argmax first-max
    }
    float hw = w * 0.5f, hh = h * 0.5f;
    float x1 = xc - hw, y1 = yc - hh, x2 = xc + hw, y2 = yc + hh;
    float off = (float)cls * MAX_WH_;
    float X1 = x1 + off, Y1 = y1 + off, X2 = x2 + off, Y2 = y2 + off;
    float area = fmaxf(X2 - X1, 0.0f) * fmaxf(Y2 - Y1, 0.0f);

    size_t o = (size_t)b * TOPK_ + rank;
    obox4[o] = make_float4(X1, Y1, X2, Y2);
    oar[o] = area;
    float* p6 = pay + o * 6;
    p6[0] = x1; p6[1] = y1; p6[2] = x2; p6[3] = y2;
    p6[4] = conf; p6[5] = (float)cls;
    valid[o] = (conf > 0.0f) ? 1 : 0;
}

// ---------------------------------------------------------------------------
// K4: TRANSPOSED suppression matrix. T[j][w] bit r = row i=w*64+r suppresses
// column j:  (j > i) && (iou(i,j) > IOU_T).  Reference FP order:
// uni = ((area_i + area_j) - inter) + 1e-7; iou = inter/uni (IEEE div).
// ---------------------------------------------------------------------------
__global__ void __launch_bounds__(256) mask_kernel(const float4* __restrict__ obox4,
                                                   const float* __restrict__ oar,
                                                   u64* __restrict__ T) {
#pragma clang fp contract(off)
    __shared__ float4 sbox[TOPK_];
    __shared__ float sar[TOPK_];
    const int b = blockIdx.y;
    const int t = threadIdx.x;
    for (int i = t; i < TOPK_; i += 256) {
        sbox[i] = obox4[(size_t)b * TOPK_ + i];
        sar[i] = oar[(size_t)b * TOPK_ + i];
    }
    __syncthreads();
    const int j = blockIdx.x * 16 + (t >> 4);   // column
    const int w = t & 15;                       // row word
    float4 bj = sbox[j];
    float aj = sar[j];
    u64 m = 0;
#pragma unroll 4
    for (int jj = 0; jj < 64; ++jj) {
        int r = (jj + 5 * w) & 63;              // stagger LDS broadcast groups
        int i = (w << 6) | r;
        float4 bi = sbox[i];
        float ai = sar[i];
        float lx = fmaxf(bi.x, bj.x);
        float ly = fmaxf(bi.y, bj.y);
        float rx = fminf(bi.z, bj.z);
        float ry = fminf(bi.w, bj.w);
        float iw = fmaxf(rx - lx, 0.0f);
        float ih = fmaxf(ry - ly, 0.0f);
        float inter = iw * ih;
        float uni = ai + aj - inter + 1e-7f;
        bool sup = (inter / uni > IOU_T) && (j > i);
        m |= sup ? (1ull << r) : 0ull;
    }
    T[((size_t)b * TOPK_ + j) * 16 + w] = m;
}

// ---------------------------------------------------------------------------
// K5: word-parallel exact greedy scan, one wave per batch.
// Per 64-row word: exact ballot fixpoint (>=1 row resolved per round).
// Cross-word suppression via 1 ballot per earlier word. Early termination
// once >=300 kept (kept scores descending, top_k stable).
// ---------------------------------------------------------------------------
__global__ void __launch_bounds__(64) scan_kernel(const u64* __restrict__ T,
                                                  const int* __restrict__ valid,
                                                  const float* __restrict__ pay,
                                                  float* __restrict__ out) {
    const int b = blockIdx.x;
    const int lane = threadIdx.x;
    u64 kept[16];
    bool done = false;
    int total = 0;

#pragma unroll
    for (int sw = 0; sw < 16; ++sw) {
        if (done) { kept[sw] = 0; continue; }
        const u64* col = T + ((size_t)(b * TOPK_ + sw * 64 + lane)) * 16;
        u64 tc[16];
#pragma unroll
        for (int q = 0; q < 8; ++q) {
            ulonglong2 v = reinterpret_cast<const ulonglong2*>(col)[q];
            tc[2 * q] = v.x;
            tc[2 * q + 1] = v.y;
        }
        int vint = valid[b * TOPK_ + sw * 64 + lane];
        u64 vw = __ballot(vint != 0);
        u64 rem_in = 0;
#pragma unroll
        for (int s = 0; s < 16; ++s) {
            if (s < sw) rem_in |= __ballot((kept[s] & tc[s]) != 0);
        }
        u64 Td = tc[sw];
        u64 K = 0;
        u64 R = (~vw) | rem_in;
        u64 U = ~(K | R);
        int guard = 0;
        while (U && guard++ < 64) {
            u64 S = Td & (K | U);
            bool inU = ((U >> lane) & 1ull) != 0;
            u64 nK = __ballot(inU && (S == 0));
            u64 nR = __ballot(inU && ((S & K) != 0));
            K |= nK;
            R |= nR;
            U &= ~(nK | nR);
        }
        kept[sw] = K;
        total += __popcll(K);
        if (total >= MAXDET_) done = true;
    }

    int cum = 0;
#pragma unroll
    for (int w = 0; w < 16; ++w) {
        u64 aw = kept[w];
        bool bit = ((aw >> lane) & 1ull) != 0;
        int rank = cum + __popcll(aw & ((1ull << lane) - 1ull));
        if (bit && rank < MAXDET_) {
            const float* p6 = pay + ((size_t)(b * TOPK_ + w * 64 + lane)) * 6;
            float* o = out + ((size_t)(b * MAXDET_ + rank)) * 6;
            o[0] = p6[0]; o[1] = p6[1]; o[2] = p6[2];
            o[3] = p6[3]; o[4] = p6[4]; o[5] = p6[5];
        }
        cum += __popcll(aw);
    }
    int kept_n = cum < MAXDET_ ? cum : MAXDET_;
    for (int i = kept_n * 6 + lane; i < MAXDET_ * 6; i += 64)
        out[(size_t)b * MAXDET_ * 6 + i] = 0.0f;
}

extern "C" void kernel_launch(void* const* d_in, const int* in_sizes, int n_in,
                              void* d_out, int out_size, void* d_ws, size_t ws_size,
                              hipStream_t stream) {
    const float* det = (const float*)d_in[0];
    float* out = (float*)d_out;
    char* ws = (char*)d_ws;

    u64* keys = (u64*)(ws + OFF_KEYS);
    u64* T = (u64*)(ws + OFF_T);       // aliases keys (dead before mask runs)
    u32* hist = (u32*)(ws + OFF_HIST);
    u64* selk = (u64*)(ws + OFF_SELK);
    float4* obox4 = (float4*)(ws + OFF_OBOX);
    float* oar = (float*)(ws + OFF_OAR);
    float* pay = (float*)(ws + OFF_PAY);
    int* valid = (int*)(ws + OFF_VALID);

    hipMemsetAsync(hist, 0, (size_t)B_ * NBINS_ * sizeof(u32), stream);
    score_kernel<<<K1_GRID, 256, 0, stream>>>(det, keys, hist);
    select_kernel<<<B_, 1024, 0, stream>>>(keys, hist, selk);
    rank_kernel<<<B_ * 16, 64, 0, stream>>>(det, selk, obox4, oar, pay, valid);
    dim3 g4(TOPK_ / 16, B_);
    mask_kernel<<<g4, 256, 0, stream>>>(obox4, oar, T);
    scan_kernel<<<B_, 64, 0, stream>>>(T, valid, pay, out);
}

// Round 7
// 135.397 us; speedup vs baseline: 4.0292x; 1.0031x over previous
//
#include <hip/hip_runtime.h>
#include <stdint.h>

#define B_ 16
#define N_ 25200
#define NC_ 80
#define ROW_ 85
#define TOPK_ 1024
#define MAXDET_ 300
#define CONF_T 0.25f
#define IOU_T 0.45f
#define MAX_WH_ 4096.0f
#define NBINS_ 16384   /* top-14-bit histogram (key bits [50:64)) */
#define CBUF_CAP 4096

typedef unsigned long long u64;
typedef unsigned int u32;

// ws layout (bytes). T (transposed suppression matrix, 2 MB) ALIASES keys
// (3.2 MB): keys are dead after select_kernel, mask_kernel runs after it.
#define OFF_KEYS  0ull                      // 16*25200*8 = 3,225,600
#define OFF_T     0ull                      // 16*1024*16*8 = 2,097,152 (alias)
#define OFF_HIST  3225600ull                // 16*16384*4 = 1,048,576
#define OFF_SELK  4274176ull                // 16*1024*8  =   131,072
#define OFF_OBOX  4405248ull                // 16*1024*16 =   262,144
#define OFF_OAR   4667392ull                // 16*1024*4  =    65,536
#define OFF_PAY   4732928ull                // 16*1024*24 =   393,216
#define OFF_VALID 5126144ull                // 16*1024*4  =    65,536  -> end 5,191,680

// ---------------------------------------------------------------------------
// K0: zero the histogram ourselves. rocclr's fillBufferAligned for this 1 MB
// memset ran at 13.7 GB/s / 77 us (launch-starved pattern kernel) and was
// graph-captured into every replay. 256 blocks x 256 thr x uint4 = 1 MB.
// ---------------------------------------------------------------------------
__global__ void __launch_bounds__(256) zero_hist(uint4* __restrict__ hist4) {
    hist4[blockIdx.x * 256 + threadIdx.x] = make_uint4(0u, 0u, 0u, 0u);
}

// ---------------------------------------------------------------------------
// K1 v4: persistent blocks + double-buffered global_load_lds (width 16) DMA.
// 64-row tiles (1360 float4). Each buffer is padded to the full 24-slot span
// (1536 float4) so EVERY slot's 64-lane write lands in-bounds. Per wave
// exactly 6 loads/tile -> vmcnt(6) after issuing the NEXT tile's loads
// guarantees the CURRENT tile is resident while the prefetch stays in
// flight (counted-vmcnt). Raw s_barrier so the prefetch isn't drained.
// key = conf_bits<<32 | (0xFFFFFFFF - n)  (unique; desc order == lax.top_k)
// ---------------------------------------------------------------------------
#define K1_ROWS 64
#define K1_TPB  ((N_ + K1_ROWS - 1) / K1_ROWS)    /* 394 tiles per batch  */
#define K1_TILES (K1_TPB * B_)                    /* 6304 tiles total     */
#define K1_GRID 768                               /* 3 blocks/CU x 256 CU */
#define K1_F4   ((K1_ROWS * ROW_) / 4)            /* 1360 live float4/tile */
#define K1_SLOTS 24                               /* 6 per wave x 4 waves  */
#define K1_BUF_F4 (K1_SLOTS * 64)                 /* 1536 float4 buffer    */

__device__ __forceinline__ void k1_stage(const float4* __restrict__ src4, int cnt4,
                                         float4* buf, int wid, int lane) {
#pragma unroll
    for (int k = 0; k < 6; ++k) {
        const int s = k * 4 + wid;                 // slot 0..23
        const int f = s * 64 + lane;
        const float4* g = src4 + min(f, cnt4 - 1); // clamp: never read past det
        float4* l = buf + s * 64;                  // wave-uniform, in-bounds
        __builtin_amdgcn_global_load_lds(
            (const __attribute__((address_space(1))) void*)g,
            (__attribute__((address_space(3))) void*)l, 16, 0, 0);
    }
}

__global__ void __launch_bounds__(256) score_kernel(const float* __restrict__ det,
                                                    u64* __restrict__ keys,
                                                    u32* __restrict__ hist) {
#pragma clang fp contract(off)
    __shared__ float4 sbuf[2 * K1_BUF_F4];         // 49,152 B -> 3 blocks/CU
    const int t = threadIdx.x;
    const int wid = t >> 6;
    const int lane = t & 63;

    int tid = blockIdx.x;
    // prologue: stage first tile into buf 0
    {
        const int b0 = tid / K1_TPB, tk0 = tid % K1_TPB;
        const int r00 = tk0 * K1_ROWS;
        const int rows0 = min(K1_ROWS, N_ - r00);
        const float4* src4 = (const float4*)(det + ((size_t)b0 * N_ + r00) * ROW_);
        k1_stage(src4, rows0 * ROW_ / 4, &sbuf[0], wid, lane);
    }
    int p = 0;
    while (tid < K1_TILES) {
        const int b = tid / K1_TPB, tk = tid % K1_TPB;
        const int r0 = tk * K1_ROWS;
        const int rows = min(K1_ROWS, N_ - r0);
        const int next = tid + K1_GRID;
        const bool has_next = (next < K1_TILES);
        if (has_next) {
            const int nb = next / K1_TPB, ntk = next % K1_TPB;
            const int nr0 = ntk * K1_ROWS;
            const int nrows = min(K1_ROWS, N_ - nr0);
            const float4* nsrc4 = (const float4*)(det + ((size_t)nb * N_ + nr0) * ROW_);
            k1_stage(nsrc4, nrows * ROW_ / 4, &sbuf[(1 - p) * K1_BUF_F4], wid, lane);
            asm volatile("s_waitcnt vmcnt(6)" ::: "memory");  // current tile done
        } else {
            asm volatile("s_waitcnt vmcnt(0)" ::: "memory");
        }
        __builtin_amdgcn_sched_barrier(0);         // nothing hoists above the wait
        __builtin_amdgcn_s_barrier();              // raw barrier: keep prefetch alive

        // compute on buf[p]: 4 lanes/row, 20 classes each, shfl-combined max
        const float* sp = (const float*)&sbuf[p * K1_BUF_F4];
        const int row = t >> 2;
        const int h = t & 3;
        const bool rv = (row < rows);
        float m = -1.0f;
        float obj = 0.0f;
        if (rv) {
            const float* rp = sp + row * ROW_;
            obj = rp[4];
#pragma unroll
            for (int c = 0; c < 20; ++c) {
                float pr = obj * rp[5 + h * 20 + c];
                m = (pr > m) ? pr : m;
            }
        }
        m = fmaxf(m, __shfl_xor(m, 1));
        m = fmaxf(m, __shfl_xor(m, 2));
        float conf = (rv && obj > CONF_T && m > CONF_T) ? m : 0.0f;
        u64 key = ((u64)__float_as_uint(conf) << 32) |
                  (u32)(0xFFFFFFFFu - (u32)(r0 + row));
        if (rv && h == 0) keys[(size_t)b * N_ + r0 + row] = key;

        u64 zb = __ballot(rv && h == 0 && conf == 0.0f);
        if (rv && h == 0) {
            if (conf != 0.0f)
                atomicAdd(&hist[b * NBINS_ + (u32)(key >> 50)], 1u);
            else if ((t & 63) == (__ffsll((long long)zb) - 1))
                atomicAdd(&hist[b * NBINS_], (u32)__popcll(zb));
        }
        __builtin_amdgcn_s_barrier();  // all reads of buf[p] done before re-stage
        p ^= 1;
        tid = next;
    }
}

// ---------------------------------------------------------------------------
// K2: exact top-1024 select, one 1024-thr block per batch.
//  A: suffix scan of 16384-bin hist (wave shfl + 1 LDS combine) -> coarse CUT
//  B: one global scan (4x unrolled) compacts keys>=CUT into LDS cbuf
//  C: 8 byte radix passes over cbuf (LDS atomics + wave-parallel digit scan)
//  D: gather exactly 1024 keys >= T into selk (unsorted)
// ---------------------------------------------------------------------------
__global__ void __launch_bounds__(1024) select_kernel(const u64* __restrict__ keys,
                                                      const u32* __restrict__ hist,
                                                      u64* __restrict__ selk) {
    const int b = blockIdx.x;
    const int t = threadIdx.x;
    const int lane = t & 63;
    const int wid = t >> 6;
    __shared__ u32 wtot[16];
    __shared__ u64 cbuf[CBUF_CAP];
    __shared__ u32 hist256[256];
    __shared__ u64 s_prefix;
    __shared__ int s_k, s_cnt, s_cutd;

    const u64* bkeys = keys + (size_t)b * N_;
    const u32* bh = hist + b * NBINS_;

    // ---- A: 16 bins/thread; wave suffix-scan + cross-wave combine ----
    u32 h[16];
    u32 csum = 0;
#pragma unroll
    for (int q = 0; q < 16; ++q) { h[q] = bh[t * 16 + q]; csum += h[q]; }
    u32 suf = csum;
#pragma unroll
    for (int off = 1; off < 64; off <<= 1) {
        u32 v = __shfl_down(suf, off);
        if (lane + off < 64) suf += v;
    }
    if (lane == 0) wtot[wid] = suf;     // wave total (suffix at lane 0)
    __syncthreads();
    u32 hi = 0;
    for (int w = wid + 1; w < 16; ++w) hi += wtot[w];
    u32 above = (suf - csum) + hi;      // sum over threads strictly after t
    u32 incl = above + csum;
    if (incl >= (u32)TOPK_ && above < (u32)TOPK_) {
        u32 cum = above;
        int cutd = t * 16;
        bool found = false;
#pragma unroll
        for (int q = 15; q >= 0; --q) {
            if (!found && cum + h[q] >= (u32)TOPK_) { cutd = t * 16 + q; found = true; }
            if (!found) cum += h[q];
        }
        s_cutd = cutd;
    }
    __syncthreads();
    const u64 CUT = ((u64)(u32)s_cutd) << 50;

    // ---- B: compact keys >= CUT into LDS (4x unrolled for MLP) ----
    if (t == 0) s_cnt = 0;
    __syncthreads();
    int n = t;
    for (; n + 3 * 1024 < N_; n += 4096) {
        u64 k0 = bkeys[n];
        u64 k1 = bkeys[n + 1024];
        u64 k2 = bkeys[n + 2048];
        u64 k3 = bkeys[n + 3072];
        if (k0 >= CUT) { int p = atomicAdd(&s_cnt, 1); if (p < CBUF_CAP) cbuf[p] = k0; }
        if (k1 >= CUT) { int p = atomicAdd(&s_cnt, 1); if (p < CBUF_CAP) cbuf[p] = k1; }
        if (k2 >= CUT) { int p = atomicAdd(&s_cnt, 1); if (p < CBUF_CAP) cbuf[p] = k2; }
        if (k3 >= CUT) { int p = atomicAdd(&s_cnt, 1); if (p < CBUF_CAP) cbuf[p] = k3; }
    }
    for (; n < N_; n += 1024) {
        u64 key = bkeys[n];
        if (key >= CUT) { int p = atomicAdd(&s_cnt, 1); if (p < CBUF_CAP) cbuf[p] = key; }
    }
    __syncthreads();
    const int cnt = min(s_cnt, CBUF_CAP);

    // ---- C: 8 radix passes entirely in LDS ----
    u64 prefix = 0;
    int k = TOPK_;
    for (int shift = 56; shift >= 0; shift -= 8) {
        if (t < 256) hist256[t] = 0;
        __syncthreads();
        for (int nn = t; nn < cnt; nn += 1024) {
            u64 key = cbuf[nn];
            if (shift == 56 || (key >> (shift + 8)) == prefix)
                atomicAdd(&hist256[(u32)(key >> shift) & 255u], 1u);
        }
        __syncthreads();
        if (t < 64) {   // wave 0: parallel digit suffix-scan, 4 bins/lane
            u32 b0 = hist256[t * 4 + 0], b1 = hist256[t * 4 + 1];
            u32 b2 = hist256[t * 4 + 2], b3 = hist256[t * 4 + 3];
            u32 sgrp = b0 + b1 + b2 + b3;
            u32 sufl = sgrp;
#pragma unroll
            for (int off = 1; off < 64; off <<= 1) {
                u32 vv = __shfl(sufl, t + off);
                sufl += (t + off < 64) ? vv : 0;
            }
            u32 A = sufl - sgrp;
            if (sufl >= (u32)k && A < (u32)k) {
                u32 cum = A;
                int d = t * 4;
                bool found = false;
                if (!found && cum + b3 >= (u32)k) { d = t * 4 + 3; found = true; }
                if (!found) { cum += b3; if (cum + b2 >= (u32)k) { d = t * 4 + 2; found = true; } }
                if (!found) { cum += b2; if (cum + b1 >= (u32)k) { d = t * 4 + 1; found = true; } }
                if (!found) { cum += b1; if (cum + b0 >= (u32)k) { d = t * 4 + 0; found = true; } }
                s_prefix = (prefix << 8) | (u64)d;
                s_k = k - (int)cum;
            }
        }
        __syncthreads();
        prefix = s_prefix;
        k = s_k;
        __syncthreads();
    }
    const u64 T64 = prefix;   // exact 1024th-largest key

    // ---- D: gather all keys >= T64 (exactly 1024, keys unique) ----
    if (t == 0) s_cnt = 0;
    __syncthreads();
    for (int nn = t; nn < cnt; nn += 1024) {
        u64 key = cbuf[nn];
        if (key >= T64) {
            int pos = atomicAdd(&s_cnt, 1);
            if (pos < TOPK_) selk[(size_t)b * TOPK_ + pos] = key;
        }
    }
}

// ---------------------------------------------------------------------------
// K3: rank the 1024 keys (brute force, 1 wave/block), gather rows, recompute
// cls/boxes with reference FP order, write into sorted slots.
// ---------------------------------------------------------------------------
__global__ void __launch_bounds__(64) rank_kernel(const float* __restrict__ det,
                                                  const u64* __restrict__ selk,
                                                  float4* __restrict__ obox4,
                                                  float* __restrict__ oar,
                                                  float* __restrict__ pay,
                                                  int* __restrict__ valid) {
#pragma clang fp contract(off)
    __shared__ u64 sk[TOPK_];
    const int b = blockIdx.x >> 4;
    const int chunk = blockIdx.x & 15;
    const int t = threadIdx.x;
    for (int i = t; i < TOPK_; i += 64) sk[i] = selk[(size_t)b * TOPK_ + i];
    __syncthreads();
    u64 myk = sk[chunk * 64 + t];
    int rank = 0;
#pragma unroll 8
    for (int i = 0; i < TOPK_; ++i) rank += (sk[i] > myk) ? 1 : 0;

    int n_idx = (int)(0xFFFFFFFFu - (u32)myk);
    float conf = __uint_as_float((u32)(myk >> 32));
    const float* row = det + ((size_t)b * N_ + n_idx) * ROW_;
    float xc = row[0], yc = row[1], w = row[2], h = row[3];
    float obj = row[4];
    float m = -1.0f;
    int cls = 0;
    for (int c = 0; c < NC_; ++c) {
        float p = obj * row[5 + c];
        if (p > m) { m = p; cls = c; }   // strict > == jnp.argmax first-max
    }
    float hw = w * 0.5f, hh = h * 0.5f;
    float x1 = xc - hw, y1 = yc - hh, x2 = xc + hw, y2 = yc + hh;
    float off = (float)cls * MAX_WH_;
    float X1 = x1 + off, Y1 = y1 + off, X2 = x2 + off, Y2 = y2 + off;
    float area = fmaxf(X2 - X1, 0.0f) * fmaxf(Y2 - Y1, 0.0f);

    size_t o = (size_t)b * TOPK_ + rank;
    obox4[o] = make_float4(X1, Y1, X2, Y2);
    oar[o] = area;
    float* p6 = pay + o * 6;
    p6[0] = x1; p6[1] = y1; p6[2] = x2; p6[3] = y2;
    p6[4] = conf; p6[5] = (float)cls;
    valid[o] = (conf > 0.0f) ? 1 : 0;
}

// ---------------------------------------------------------------------------
// K4: TRANSPOSED suppression matrix. T[j][w] bit r = row i=w*64+r suppresses
// column j:  (j > i) && (iou(i,j) > IOU_T).  Reference FP order:
// uni = ((area_i + area_j) - inter) + 1e-7; iou = inter/uni (IEEE div).
// ---------------------------------------------------------------------------
__global__ void __launch_bounds__(256) mask_kernel(const float4* __restrict__ obox4,
                                                   const float* __restrict__ oar,
                                                   u64* __restrict__ T) {
#pragma clang fp contract(off)
    __shared__ float4 sbox[TOPK_];
    __shared__ float sar[TOPK_];
    const int b = blockIdx.y;
    const int t = threadIdx.x;
    for (int i = t; i < TOPK_; i += 256) {
        sbox[i] = obox4[(size_t)b * TOPK_ + i];
        sar[i] = oar[(size_t)b * TOPK_ + i];
    }
    __syncthreads();
    const int j = blockIdx.x * 16 + (t >> 4);   // column
    const int w = t & 15;                       // row word
    float4 bj = sbox[j];
    float aj = sar[j];
    u64 m = 0;
#pragma unroll 4
    for (int jj = 0; jj < 64; ++jj) {
        int r = (jj + 5 * w) & 63;              // stagger LDS broadcast groups
        int i = (w << 6) | r;
        float4 bi = sbox[i];
        float ai = sar[i];
        float lx = fmaxf(bi.x, bj.x);
        float ly = fmaxf(bi.y, bj.y);
        float rx = fminf(bi.z, bj.z);
        float ry = fminf(bi.w, bj.w);
        float iw = fmaxf(rx - lx, 0.0f);
        float ih = fmaxf(ry - ly, 0.0f);
        float inter = iw * ih;
        float uni = ai + aj - inter + 1e-7f;
        bool sup = (inter / uni > IOU_T) && (j > i);
        m |= sup ? (1ull << r) : 0ull;
    }
    T[((size_t)b * TOPK_ + j) * 16 + w] = m;
}

// ---------------------------------------------------------------------------
// K5: word-parallel exact greedy scan, one wave per batch.
// Per 64-row word: exact ballot fixpoint (>=1 row resolved per round).
// Cross-word suppression via 1 ballot per earlier word. Early termination
// once >=300 kept (kept scores descending, top_k stable).
// ---------------------------------------------------------------------------
__global__ void __launch_bounds__(64) scan_kernel(const u64* __restrict__ T,
                                                  const int* __restrict__ valid,
                                                  const float* __restrict__ pay,
                                                  float* __restrict__ out) {
    const int b = blockIdx.x;
    const int lane = threadIdx.x;
    u64 kept[16];
    bool done = false;
    int total = 0;

#pragma unroll
    for (int sw = 0; sw < 16; ++sw) {
        if (done) { kept[sw] = 0; continue; }
        const u64* col = T + ((size_t)(b * TOPK_ + sw * 64 + lane)) * 16;
        u64 tc[16];
#pragma unroll
        for (int q = 0; q < 8; ++q) {
            ulonglong2 v = reinterpret_cast<const ulonglong2*>(col)[q];
            tc[2 * q] = v.x;
            tc[2 * q + 1] = v.y;
        }
        int vint = valid[b * TOPK_ + sw * 64 + lane];
        u64 vw = __ballot(vint != 0);
        u64 rem_in = 0;
#pragma unroll
        for (int s = 0; s < 16; ++s) {
            if (s < sw) rem_in |= __ballot((kept[s] & tc[s]) != 0);
        }
        u64 Td = tc[sw];
        u64 K = 0;
        u64 R = (~vw) | rem_in;
        u64 U = ~(K | R);
        int guard = 0;
        while (U && guard++ < 64) {
            u64 S = Td & (K | U);
            bool inU = ((U >> lane) & 1ull) != 0;
            u64 nK = __ballot(inU && (S == 0));
            u64 nR = __ballot(inU && ((S & K) != 0));
            K |= nK;
            R |= nR;
            U &= ~(nK | nR);
        }
        kept[sw] = K;
        total += __popcll(K);
        if (total >= MAXDET_) done = true;
    }

    int cum = 0;
#pragma unroll
    for (int w = 0; w < 16; ++w) {
        u64 aw = kept[w];
        bool bit = ((aw >> lane) & 1ull) != 0;
        int rank = cum + __popcll(aw & ((1ull << lane) - 1ull));
        if (bit && rank < MAXDET_) {
            const float* p6 = pay + ((size_t)(b * TOPK_ + w * 64 + lane)) * 6;
            float* o = out + ((size_t)(b * MAXDET_ + rank)) * 6;
            o[0] = p6[0]; o[1] = p6[1]; o[2] = p6[2];
            o[3] = p6[3]; o[4] = p6[4]; o[5] = p6[5];
        }
        cum += __popcll(aw);
    }
    int kept_n = cum < MAXDET_ ? cum : MAXDET_;
    for (int i = kept_n * 6 + lane; i < MAXDET_ * 6; i += 64)
        out[(size_t)b * MAXDET_ * 6 + i] = 0.0f;
}

extern "C" void kernel_launch(void* const* d_in, const int* in_sizes, int n_in,
                              void* d_out, int out_size, void* d_ws, size_t ws_size,
                              hipStream_t stream) {
    const float* det = (const float*)d_in[0];
    float* out = (float*)d_out;
    char* ws = (char*)d_ws;

    u64* keys = (u64*)(ws + OFF_KEYS);
    u64* T = (u64*)(ws + OFF_T);       // aliases keys (dead before mask runs)
    u32* hist = (u32*)(ws + OFF_HIST);
    u64* selk = (u64*)(ws + OFF_SELK);
    float4* obox4 = (float4*)(ws + OFF_OBOX);
    float* oar = (float*)(ws + OFF_OAR);
    float* pay = (float*)(ws + OFF_PAY);
    int* valid = (int*)(ws + OFF_VALID);

    zero_hist<<<(B_ * NBINS_ * 4) / (256 * 16), 256, 0, stream>>>((uint4*)hist);
    score_kernel<<<K1_GRID, 256, 0, stream>>>(det, keys, hist);
    select_kernel<<<B_, 1024, 0, stream>>>(keys, hist, selk);
    rank_kernel<<<B_ * 16, 64, 0, stream>>>(det, selk, obox4, oar, pay, valid);
    dim3 g4(TOPK_ / 16, B_);
    mask_kernel<<<g4, 256, 0, stream>>>(obox4, oar, T);
    scan_kernel<<<B_, 64, 0, stream>>>(T, valid, pay, out);
}

// Round 8
// 99.259 us; speedup vs baseline: 5.4961x; 1.3641x over previous
//
#include <hip/hip_runtime.h>
#include <stdint.h>

#define B_ 16
#define N_ 25200
#define NC_ 80
#define ROW_ 85
#define TOPK_ 1024
#define MAXDET_ 300
#define CONF_T 0.25f
#define IOU_T 0.45f
#define MAX_WH_ 4096.0f
#define NBINS_ 16384   /* LDS histogram of key bits [44:58) == conf bits [12:26) */
#define CBUF_CAP 4096

typedef unsigned long long u64;
typedef unsigned int u32;

// ws layout (bytes). T (transposed suppression matrix, 2 MB) ALIASES keys
// (3.2 MB): keys are dead after select_kernel, mask_kernel runs after it.
#define OFF_KEYS  0ull                      // 16*25200*8 = 3,225,600
#define OFF_T     0ull                      // 16*1024*16*8 = 2,097,152 (alias)
#define OFF_OBOX  3225600ull                // 16*1024*16 =   262,144
#define OFF_OAR   3487744ull                // 16*1024*4  =    65,536
#define OFF_PAY   3553280ull                // 16*1024*24 =   393,216
#define OFF_VALID 3946496ull                // 16*1024*4  =    65,536  -> end 4,012,032

// ---------------------------------------------------------------------------
// K1 v5: persistent blocks + double-buffered global_load_lds DMA (unchanged
// from v4 except: NO histogram atomics — pure streaming keys producer).
// key = conf_bits<<32 | (0xFFFFFFFF - n)  (unique; desc order == lax.top_k)
// ---------------------------------------------------------------------------
#define K1_ROWS 64
#define K1_TPB  ((N_ + K1_ROWS - 1) / K1_ROWS)    /* 394 tiles per batch  */
#define K1_TILES (K1_TPB * B_)                    /* 6304 tiles total     */
#define K1_GRID 768                               /* 3 blocks/CU x 256 CU */
#define K1_SLOTS 24                               /* 6 per wave x 4 waves  */
#define K1_BUF_F4 (K1_SLOTS * 64)                 /* 1536 float4 buffer    */

__device__ __forceinline__ void k1_stage(const float4* __restrict__ src4, int cnt4,
                                         float4* buf, int wid, int lane) {
#pragma unroll
    for (int k = 0; k < 6; ++k) {
        const int s = k * 4 + wid;                 // slot 0..23
        const int f = s * 64 + lane;
        const float4* g = src4 + min(f, cnt4 - 1); // clamp: never read past det
        float4* l = buf + s * 64;                  // wave-uniform, in-bounds
        __builtin_amdgcn_global_load_lds(
            (const __attribute__((address_space(1))) void*)g,
            (__attribute__((address_space(3))) void*)l, 16, 0, 0);
    }
}

__global__ void __launch_bounds__(256) score_kernel(const float* __restrict__ det,
                                                    u64* __restrict__ keys) {
#pragma clang fp contract(off)
    __shared__ float4 sbuf[2 * K1_BUF_F4];         // 49,152 B -> 3 blocks/CU
    const int t = threadIdx.x;
    const int wid = t >> 6;
    const int lane = t & 63;

    int tid = blockIdx.x;
    {
        const int b0 = tid / K1_TPB, tk0 = tid % K1_TPB;
        const int r00 = tk0 * K1_ROWS;
        const int rows0 = min(K1_ROWS, N_ - r00);
        const float4* src4 = (const float4*)(det + ((size_t)b0 * N_ + r00) * ROW_);
        k1_stage(src4, rows0 * ROW_ / 4, &sbuf[0], wid, lane);
    }
    int p = 0;
    while (tid < K1_TILES) {
        const int b = tid / K1_TPB, tk = tid % K1_TPB;
        const int r0 = tk * K1_ROWS;
        const int rows = min(K1_ROWS, N_ - r0);
        const int next = tid + K1_GRID;
        const bool has_next = (next < K1_TILES);
        if (has_next) {
            const int nb = next / K1_TPB, ntk = next % K1_TPB;
            const int nr0 = ntk * K1_ROWS;
            const int nrows = min(K1_ROWS, N_ - nr0);
            const float4* nsrc4 = (const float4*)(det + ((size_t)nb * N_ + nr0) * ROW_);
            k1_stage(nsrc4, nrows * ROW_ / 4, &sbuf[(1 - p) * K1_BUF_F4], wid, lane);
            asm volatile("s_waitcnt vmcnt(6)" ::: "memory");  // current tile done
        } else {
            asm volatile("s_waitcnt vmcnt(0)" ::: "memory");
        }
        __builtin_amdgcn_sched_barrier(0);
        __builtin_amdgcn_s_barrier();

        const float* sp = (const float*)&sbuf[p * K1_BUF_F4];
        const int row = t >> 2;
        const int h = t & 3;
        const bool rv = (row < rows);
        float m = -1.0f;
        float obj = 0.0f;
        if (rv) {
            const float* rp = sp + row * ROW_;
            obj = rp[4];
#pragma unroll
            for (int c = 0; c < 20; ++c) {
                float pr = obj * rp[5 + h * 20 + c];
                m = (pr > m) ? pr : m;
            }
        }
        m = fmaxf(m, __shfl_xor(m, 1));
        m = fmaxf(m, __shfl_xor(m, 2));
        float conf = (rv && obj > CONF_T && m > CONF_T) ? m : 0.0f;
        u64 key = ((u64)__float_as_uint(conf) << 32) |
                  (u32)(0xFFFFFFFFu - (u32)(r0 + row));
        if (rv && h == 0) keys[(size_t)b * N_ + r0 + row] = key;

        __builtin_amdgcn_s_barrier();  // all reads of buf[p] done before re-stage
        p ^= 1;
        tid = next;
    }
}

// ---------------------------------------------------------------------------
// K2 v3: select + sort + gather fused. One 1024-thr block per batch.
//  A: LDS 16K-bin hist of NONZERO keys (bin = key bits [44:58); monotone
//     because conf>0.25 fixes conf float bits [26:32) = 15)
//  B: suffix scan -> coarse cutd (count in [1024, ~1100])
//  C: global compact (nonzero && bin>=cutd) into LDS cbuf
//  D: exact 8-pass radix select of 1024th key among cbuf; gather top-1024
//  E: bitonic sort 1024 keys descending (unique keys -> exact, deterministic)
//  F: thread t = rank t: gather det row, recompute cls/box (reference FP
//     order), write obox/oar/pay/valid
// ---------------------------------------------------------------------------
__global__ void __launch_bounds__(1024) select_kernel(const u64* __restrict__ keys,
                                                      const float* __restrict__ det,
                                                      float4* __restrict__ obox4,
                                                      float* __restrict__ oar,
                                                      float* __restrict__ pay,
                                                      int* __restrict__ valid) {
#pragma clang fp contract(off)
    const int b = blockIdx.x;
    const int t = threadIdx.x;
    const int lane = t & 63;
    const int wid = t >> 6;
    __shared__ u32 hist16k[NBINS_];      // 64 KB
    __shared__ u64 cbuf[CBUF_CAP];       // 32 KB
    __shared__ u64 sorted[TOPK_];        // 8 KB
    __shared__ u32 hist256[256];
    __shared__ u32 wtot[16];
    __shared__ u64 s_prefix;
    __shared__ int s_k, s_cnt, s_cutd, s_total;

    const u64* bkeys = keys + (size_t)b * N_;

    // ---- A: LDS histogram ----
    for (int i = t; i < NBINS_; i += 1024) hist16k[i] = 0;
    __syncthreads();
    for (int n = t; n < N_; n += 1024) {
        u64 key = bkeys[n];
        if ((key >> 32) != 0)
            atomicAdd(&hist16k[(u32)(key >> 44) & (NBINS_ - 1)], 1u);
    }
    __syncthreads();

    // ---- B: suffix scan (16 bins/thread; wave shfl + cross-wave) ----
    u32 h[16];
    u32 csum = 0;
#pragma unroll
    for (int q = 0; q < 16; ++q) { h[q] = hist16k[t * 16 + q]; csum += h[q]; }
    u32 suf = csum;
#pragma unroll
    for (int off = 1; off < 64; off <<= 1) {
        u32 v = __shfl_down(suf, off);
        if (lane + off < 64) suf += v;
    }
    if (lane == 0) wtot[wid] = suf;
    __syncthreads();
    if (t == 0) {
        u32 tot = 0;
        for (int w = 0; w < 16; ++w) tot += wtot[w];
        s_total = (int)tot;
        s_cutd = 0;
    }
    __syncthreads();
    u32 hi = 0;
    for (int w = wid + 1; w < 16; ++w) hi += wtot[w];
    u32 above = (suf - csum) + hi;
    u32 incl = above + csum;
    if (incl >= (u32)TOPK_ && above < (u32)TOPK_) {
        u32 cum = above;
        int cutd = t * 16;
        bool found = false;
#pragma unroll
        for (int q = 15; q >= 0; --q) {
            if (!found && cum + h[q] >= (u32)TOPK_) { cutd = t * 16 + q; found = true; }
            if (!found) cum += h[q];
        }
        s_cutd = cutd;
    }
    __syncthreads();
    const u32 cutd = (u32)s_cutd;
    const int total = s_total;

    // ---- C: compact candidates into LDS (4x unrolled) ----
    if (t == 0) s_cnt = 0;
    __syncthreads();
    {
        int n = t;
        for (; n + 3 * 1024 < N_; n += 4096) {
            u64 k0 = bkeys[n];
            u64 k1 = bkeys[n + 1024];
            u64 k2 = bkeys[n + 2048];
            u64 k3 = bkeys[n + 3072];
            if ((k0 >> 32) != 0 && ((u32)(k0 >> 44) & (NBINS_ - 1)) >= cutd) { int p = atomicAdd(&s_cnt, 1); if (p < CBUF_CAP) cbuf[p] = k0; }
            if ((k1 >> 32) != 0 && ((u32)(k1 >> 44) & (NBINS_ - 1)) >= cutd) { int p = atomicAdd(&s_cnt, 1); if (p < CBUF_CAP) cbuf[p] = k1; }
            if ((k2 >> 32) != 0 && ((u32)(k2 >> 44) & (NBINS_ - 1)) >= cutd) { int p = atomicAdd(&s_cnt, 1); if (p < CBUF_CAP) cbuf[p] = k2; }
            if ((k3 >> 32) != 0 && ((u32)(k3 >> 44) & (NBINS_ - 1)) >= cutd) { int p = atomicAdd(&s_cnt, 1); if (p < CBUF_CAP) cbuf[p] = k3; }
        }
        for (; n < N_; n += 1024) {
            u64 key = bkeys[n];
            if ((key >> 32) != 0 && ((u32)(key >> 44) & (NBINS_ - 1)) >= cutd) { int p = atomicAdd(&s_cnt, 1); if (p < CBUF_CAP) cbuf[p] = key; }
        }
    }
    __syncthreads();
    const int cnt = min(s_cnt, CBUF_CAP);

    if (total >= TOPK_) {
        // ---- D: exact radix select of 1024th-largest among cbuf ----
        u64 prefix = 0;
        int k = TOPK_;
        for (int shift = 56; shift >= 0; shift -= 8) {
            if (t < 256) hist256[t] = 0;
            __syncthreads();
            for (int nn = t; nn < cnt; nn += 1024) {
                u64 key = cbuf[nn];
                if (shift == 56 || (key >> (shift + 8)) == prefix)
                    atomicAdd(&hist256[(u32)(key >> shift) & 255u], 1u);
            }
            __syncthreads();
            if (t < 64) {   // wave 0: parallel digit suffix-scan, 4 bins/lane
                u32 b0 = hist256[t * 4 + 0], b1 = hist256[t * 4 + 1];
                u32 b2 = hist256[t * 4 + 2], b3 = hist256[t * 4 + 3];
                u32 sgrp = b0 + b1 + b2 + b3;
                u32 sufl = sgrp;
#pragma unroll
                for (int off = 1; off < 64; off <<= 1) {
                    u32 vv = __shfl(sufl, t + off);
                    sufl += (t + off < 64) ? vv : 0;
                }
                u32 A = sufl - sgrp;
                if (sufl >= (u32)k && A < (u32)k) {
                    u32 cum = A;
                    int d = t * 4;
                    bool found = false;
                    if (!found && cum + b3 >= (u32)k) { d = t * 4 + 3; found = true; }
                    if (!found) { cum += b3; if (cum + b2 >= (u32)k) { d = t * 4 + 2; found = true; } }
                    if (!found) { cum += b2; if (cum + b1 >= (u32)k) { d = t * 4 + 1; found = true; } }
                    if (!found) { cum += b1; if (cum + b0 >= (u32)k) { d = t * 4 + 0; found = true; } }
                    s_prefix = (prefix << 8) | (u64)d;
                    s_k = k - (int)cum;
                }
            }
            __syncthreads();
            prefix = s_prefix;
            k = s_k;
            __syncthreads();
        }
        const u64 T64 = prefix;

        if (t == 0) s_cnt = 0;
        __syncthreads();
        for (int nn = t; nn < cnt; nn += 1024) {
            u64 key = cbuf[nn];
            if (key >= T64) {
                int pos = atomicAdd(&s_cnt, 1);
                if (pos < TOPK_) sorted[pos] = key;
            }
        }
        __syncthreads();
    } else {
        // fallback (< 1024 valid): real keys + conf=0 fillers (valid=0,
        // never output, never suppress — matches reference semantics)
        for (int i = t; i < TOPK_; i += 1024)
            sorted[i] = (i < cnt) ? cbuf[i] : (u64)(u32)(0xFFFFFFFFu - (u32)i);
        __syncthreads();
    }

    // ---- E: bitonic sort descending (unique keys -> exact total order) ----
    for (int kk = 2; kk <= TOPK_; kk <<= 1) {
        for (int j = kk >> 1; j > 0; j >>= 1) {
            __syncthreads();
            int partner = t ^ j;
            if (partner > t) {
                u64 a = sorted[t], c = sorted[partner];
                bool desc = ((t & kk) == 0);
                if (desc ? (a < c) : (a > c)) { sorted[t] = c; sorted[partner] = a; }
            }
        }
    }
    __syncthreads();

    // ---- F: rank t = thread t: gather row, recompute, write ----
    u64 myk = sorted[t];
    int n_idx = (int)(0xFFFFFFFFu - (u32)myk);
    float conf = __uint_as_float((u32)(myk >> 32));
    const float* row = det + ((size_t)b * N_ + n_idx) * ROW_;
    float xc = row[0], yc = row[1], w = row[2], hh2 = row[3];
    float obj = row[4];
    float m = -1.0f;
    int cls = 0;
    for (int c = 0; c < NC_; ++c) {
        float p = obj * row[5 + c];
        if (p > m) { m = p; cls = c; }   // strict > == jnp.argmax first-max
    }
    float hw = w * 0.5f, hh = hh2 * 0.5f;
    float x1 = xc - hw, y1 = yc - hh, x2 = xc + hw, y2 = yc + hh;
    float off = (float)cls * MAX_WH_;
    float X1 = x1 + off, Y1 = y1 + off, X2 = x2 + off, Y2 = y2 + off;
    float area = fmaxf(X2 - X1, 0.0f) * fmaxf(Y2 - Y1, 0.0f);

    size_t o = (size_t)b * TOPK_ + t;
    obox4[o] = make_float4(X1, Y1, X2, Y2);
    oar[o] = area;
    float* p6 = pay + o * 6;
    p6[0] = x1; p6[1] = y1; p6[2] = x2; p6[3] = y2;
    p6[4] = conf; p6[5] = (float)cls;
    valid[o] = (conf > 0.0f) ? 1 : 0;
}

// ---------------------------------------------------------------------------
// K4: TRANSPOSED suppression matrix. T[j][w] bit r = row i=w*64+r suppresses
// column j:  (j > i) && (iou(i,j) > IOU_T).  Reference FP order:
// uni = ((area_i + area_j) - inter) + 1e-7; iou = inter/uni (IEEE div).
// ---------------------------------------------------------------------------
__global__ void __launch_bounds__(256) mask_kernel(const float4* __restrict__ obox4,
                                                   const float* __restrict__ oar,
                                                   u64* __restrict__ T) {
#pragma clang fp contract(off)
    __shared__ float4 sbox[TOPK_];
    __shared__ float sar[TOPK_];
    const int b = blockIdx.y;
    const int t = threadIdx.x;
    for (int i = t; i < TOPK_; i += 256) {
        sbox[i] = obox4[(size_t)b * TOPK_ + i];
        sar[i] = oar[(size_t)b * TOPK_ + i];
    }
    __syncthreads();
    const int j = blockIdx.x * 16 + (t >> 4);   // column
    const int w = t & 15;                       // row word
    float4 bj = sbox[j];
    float aj = sar[j];
    u64 m = 0;
#pragma unroll 4
    for (int jj = 0; jj < 64; ++jj) {
        int r = (jj + 5 * w) & 63;              // stagger LDS broadcast groups
        int i = (w << 6) | r;
        float4 bi = sbox[i];
        float ai = sar[i];
        float lx = fmaxf(bi.x, bj.x);
        float ly = fmaxf(bi.y, bj.y);
        float rx = fminf(bi.z, bj.z);
        float ry = fminf(bi.w, bj.w);
        float iw = fmaxf(rx - lx, 0.0f);
        float ih = fmaxf(ry - ly, 0.0f);
        float inter = iw * ih;
        float uni = ai + aj - inter + 1e-7f;
        bool sup = (inter / uni > IOU_T) && (j > i);
        m |= sup ? (1ull << r) : 0ull;
    }
    T[((size_t)b * TOPK_ + j) * 16 + w] = m;
}

// ---------------------------------------------------------------------------
// K5: word-parallel exact greedy scan, one wave per batch.
// ---------------------------------------------------------------------------
__global__ void __launch_bounds__(64) scan_kernel(const u64* __restrict__ T,
                                                  const int* __restrict__ valid,
                                                  const float* __restrict__ pay,
                                                  float* __restrict__ out) {
    const int b = blockIdx.x;
    const int lane = threadIdx.x;
    u64 kept[16];
    bool done = false;
    int total = 0;

#pragma unroll
    for (int sw = 0; sw < 16; ++sw) {
        if (done) { kept[sw] = 0; continue; }
        const u64* col = T + ((size_t)(b * TOPK_ + sw * 64 + lane)) * 16;
        u64 tc[16];
#pragma unroll
        for (int q = 0; q < 8; ++q) {
            ulonglong2 v = reinterpret_cast<const ulonglong2*>(col)[q];
            tc[2 * q] = v.x;
            tc[2 * q + 1] = v.y;
        }
        int vint = valid[b * TOPK_ + sw * 64 + lane];
        u64 vw = __ballot(vint != 0);
        u64 rem_in = 0;
#pragma unroll
        for (int s = 0; s < 16; ++s) {
            if (s < sw) rem_in |= __ballot((kept[s] & tc[s]) != 0);
        }
        u64 Td = tc[sw];
        u64 K = 0;
        u64 R = (~vw) | rem_in;
        u64 U = ~(K | R);
        int guard = 0;
        while (U && guard++ < 64) {
            u64 S = Td & (K | U);
            bool inU = ((U >> lane) & 1ull) != 0;
            u64 nK = __ballot(inU && (S == 0));
            u64 nR = __ballot(inU && ((S & K) != 0));
            K |= nK;
            R |= nR;
            U &= ~(nK | nR);
        }
        kept[sw] = K;
        total += __popcll(K);
        if (total >= MAXDET_) done = true;
    }

    int cum = 0;
#pragma unroll
    for (int w = 0; w < 16; ++w) {
        u64 aw = kept[w];
        bool bit = ((aw >> lane) & 1ull) != 0;
        int rank = cum + __popcll(aw & ((1ull << lane) - 1ull));
        if (bit && rank < MAXDET_) {
            const float* p6 = pay + ((size_t)(b * TOPK_ + w * 64 + lane)) * 6;
            float* o = out + ((size_t)(b * MAXDET_ + rank)) * 6;
            o[0] = p6[0]; o[1] = p6[1]; o[2] = p6[2];
            o[3] = p6[3]; o[4] = p6[4]; o[5] = p6[5];
        }
        cum += __popcll(aw);
    }
    int kept_n = cum < MAXDET_ ? cum : MAXDET_;
    for (int i = kept_n * 6 + lane; i < MAXDET_ * 6; i += 64)
        out[(size_t)b * MAXDET_ * 6 + i] = 0.0f;
}

extern "C" void kernel_launch(void* const* d_in, const int* in_sizes, int n_in,
                              void* d_out, int out_size, void* d_ws, size_t ws_size,
                              hipStream_t stream) {
    const float* det = (const float*)d_in[0];
    float* out = (float*)d_out;
    char* ws = (char*)d_ws;

    u64* keys = (u64*)(ws + OFF_KEYS);
    u64* T = (u64*)(ws + OFF_T);       // aliases keys (dead before mask runs)
    float4* obox4 = (float4*)(ws + OFF_OBOX);
    float* oar = (float*)(ws + OFF_OAR);
    float* pay = (float*)(ws + OFF_PAY);
    int* valid = (int*)(ws + OFF_VALID);

    score_kernel<<<K1_GRID, 256, 0, stream>>>(det, keys);
    select_kernel<<<B_, 1024, 0, stream>>>(keys, det, obox4, oar, pay, valid);
    dim3 g4(TOPK_ / 16, B_);
    mask_kernel<<<g4, 256, 0, stream>>>(obox4, oar, T);
    scan_kernel<<<B_, 64, 0, stream>>>(T, valid, pay, out);
}